// Round 1
// baseline (2062.334 us; speedup 1.0000x reference)
//
#include <hip/hip_runtime.h>
#include <hip/hip_bf16.h>

// ---------- types ----------
typedef __attribute__((ext_vector_type(8))) __bf16 bf16x8;
typedef __attribute__((ext_vector_type(4))) float f32x4;

typedef unsigned short u16;

__device__ __forceinline__ u16 f2bf(float f) {
    unsigned int u = __float_as_uint(f);
    u += 0x7FFFu + ((u >> 16) & 1u);   // round-to-nearest-even
    return (u16)(u >> 16);
}

__device__ __forceinline__ void g2l16(const void* g, void* l) {
    __builtin_amdgcn_global_load_lds(
        (const __attribute__((address_space(1))) void*)g,
        (__attribute__((address_space(3))) void*)l, 16, 0, 0);
}

// ---------- constants ----------
#define BB 8
#define SS 1024
#define EE 768
#define HH 12
#define HD 64
#define LL 4

// ---------- fp32 -> bf16 convert ----------
__global__ __launch_bounds__(256) void cvt_k(const float* __restrict__ in,
                                             u16* __restrict__ out, int n4) {
    for (int i = blockIdx.x * 256 + threadIdx.x; i < n4; i += gridDim.x * 256) {
        float4 v = ((const float4*)in)[i];
        ushort4 u;
        u.x = f2bf(v.x); u.y = f2bf(v.y); u.z = f2bf(v.z); u.w = f2bf(v.w);
        ((ushort4*)out)[i] = u;
    }
}

// ---------- embed: h = x + wpe[study_date] ----------
__global__ __launch_bounds__(256) void embed_k(const float* __restrict__ x,
                                               const int* __restrict__ sd,
                                               const float* __restrict__ wpe,
                                               float* __restrict__ h) {
    int idx = blockIdx.x * 256 + threadIdx.x;          // over 8192*192 float4s
    int e4 = idx % 192;
    int bs = idx / 192;
    int b = bs >> 10;
    int t = (bs >> 5) & 31;
    int date = sd[b * 32 + t];
    date = date < 0 ? 0 : (date > 49 ? 49 : date);
    float4 xv = ((const float4*)x)[idx];
    float4 pv = ((const float4*)wpe)[date * 192 + e4];
    float4 r; r.x = xv.x + pv.x; r.y = xv.y + pv.y; r.z = xv.z + pv.z; r.w = xv.w + pv.w;
    ((float4*)h)[idx] = r;
}

// ---------- layernorm: wave per token ----------
template <bool BF16OUT>
__global__ __launch_bounds__(256) void ln_k(const float* __restrict__ in,
                                            const float* __restrict__ w,
                                            const float* __restrict__ b,
                                            void* __restrict__ out) {
    int tid = threadIdx.x, wv = tid >> 6, lane = tid & 63;
    int token = blockIdx.x * 4 + wv;
    const float4* ip = (const float4*)(in + (size_t)token * EE);
    float4 v[3];
#pragma unroll
    for (int p = 0; p < 3; p++) v[p] = ip[p * 64 + lane];
    float s = 0.f;
#pragma unroll
    for (int p = 0; p < 3; p++) s += v[p].x + v[p].y + v[p].z + v[p].w;
#pragma unroll
    for (int m = 1; m < 64; m <<= 1) s += __shfl_xor(s, m);
    float mean = s * (1.f / 768.f);
    float vs = 0.f;
#pragma unroll
    for (int p = 0; p < 3; p++) {
        float dx = v[p].x - mean, dy = v[p].y - mean, dz = v[p].z - mean, dw = v[p].w - mean;
        vs += dx * dx + dy * dy + dz * dz + dw * dw;
    }
#pragma unroll
    for (int m = 1; m < 64; m <<= 1) vs += __shfl_xor(vs, m);
    float rstd = rsqrtf(vs * (1.f / 768.f) + 1e-5f);
    const float4* wp = (const float4*)w;
    const float4* bp = (const float4*)b;
#pragma unroll
    for (int p = 0; p < 3; p++) {
        float4 wv4 = wp[p * 64 + lane], bv4 = bp[p * 64 + lane];
        float rx = (v[p].x - mean) * rstd * wv4.x + bv4.x;
        float ry = (v[p].y - mean) * rstd * wv4.y + bv4.y;
        float rz = (v[p].z - mean) * rstd * wv4.z + bv4.z;
        float rw = (v[p].w - mean) * rstd * wv4.w + bv4.w;
        if (BF16OUT) {
            ushort4 u; u.x = f2bf(rx); u.y = f2bf(ry); u.z = f2bf(rz); u.w = f2bf(rw);
            ((ushort4*)((u16*)out + (size_t)token * EE))[p * 64 + lane] = u;
        } else {
            float4 r; r.x = rx; r.y = ry; r.z = rz; r.w = rw;
            ((float4*)((float*)out + (size_t)token * EE))[p * 64 + lane] = r;
        }
    }
}

// ---------- GEMM: C[M,N] = A[M,K](bf16) * Bw[N,K]^T(bf16) + bias ----------
// MODE 0: QKV epilogue  (q,k -> outb [M,2304]; v -> vT transposed [B,H,HD,S])
// MODE 1: residual      (hres[M,N] += C + bias)
// MODE 2: NewGELU       (outb[M,N] = bf16(gelu(C + bias)))
template <int MODE>
__global__ __launch_bounds__(256) void gemm_bt(const u16* __restrict__ A,
                                               const u16* __restrict__ Bw,
                                               const float* __restrict__ bias,
                                               float* __restrict__ hres,
                                               u16* __restrict__ outb,
                                               u16* __restrict__ vT,
                                               int M, int N, int K) {
    __shared__ u16 As[4096];  // 128 rows x 32 cols, 16B-chunk swizzled
    __shared__ u16 Bs[4096];
    const int tid = threadIdx.x;
    const int lane = tid & 63, w = tid >> 6;
    const int quad = lane >> 4, l16 = lane & 15;
    const int m0 = blockIdx.y * 128, n0 = blockIdx.x * 128;
    const int wm = (w >> 1) * 64, wn = (w & 1) * 64;

    f32x4 acc[4][4];
#pragma unroll
    for (int i = 0; i < 4; i++)
#pragma unroll
        for (int j = 0; j < 4; j++) acc[i][j] = (f32x4){0.f, 0.f, 0.f, 0.f};

    // staging: chunk c holds A[m0 + (c>>2)][kb + 8*((c&3)^((c>>3)&3)) .. +8)
    const int c0 = w * 128 + lane;
    const int c1 = c0 + 64;
    const int rA0 = c0 >> 2, g0 = (((c0 & 3) ^ ((c0 >> 3) & 3)) * 8);
    const int rA1 = c1 >> 2, g1 = (((c1 & 3) ^ ((c1 >> 3) & 3)) * 8);
    const u16* Ap0 = A + (size_t)(m0 + rA0) * K + g0;
    const u16* Ap1 = A + (size_t)(m0 + rA1) * K + g1;
    const u16* Bp0 = Bw + (size_t)(n0 + rA0) * K + g0;
    const u16* Bp1 = Bw + (size_t)(n0 + rA1) * K + g1;
    char* lA0 = (char*)As + (w * 128) * 16;
    char* lA1 = (char*)As + (w * 128 + 64) * 16;
    char* lB0 = (char*)Bs + (w * 128) * 16;
    char* lB1 = (char*)Bs + (w * 128 + 64) * 16;

    const int swz = (quad ^ ((l16 >> 1) & 3)) * 8;

    for (int kb = 0; kb < K; kb += 32) {
        g2l16(Ap0 + kb, lA0);
        g2l16(Ap1 + kb, lA1);
        g2l16(Bp0 + kb, lB0);
        g2l16(Bp1 + kb, lB1);
        __syncthreads();
        bf16x8 af[4], bfr[4];
#pragma unroll
        for (int t = 0; t < 4; t++) {
            int rowA = wm + t * 16 + l16;
            af[t] = *(const bf16x8*)(As + rowA * 32 + swz);
            int rowB = wn + t * 16 + l16;
            bfr[t] = *(const bf16x8*)(Bs + rowB * 32 + swz);
        }
#pragma unroll
        for (int tm = 0; tm < 4; tm++)
#pragma unroll
            for (int tn = 0; tn < 4; tn++)
                acc[tm][tn] = __builtin_amdgcn_mfma_f32_16x16x32_bf16(
                    af[tm], bfr[tn], acc[tm][tn], 0, 0, 0);
        __syncthreads();
    }

    // epilogue: C row = m0+wm+tm*16+quad*4+r ; col = n0+wn+tn*16+l16
#pragma unroll
    for (int tm = 0; tm < 4; tm++) {
        int rowm = m0 + wm + tm * 16 + quad * 4;
#pragma unroll
        for (int tn = 0; tn < 4; tn++) {
            int coln = n0 + wn + tn * 16 + l16;
            float bv = bias[coln];
            f32x4 v = acc[tm][tn];
            if (MODE == 0) {
                if (coln < 2 * EE) {
#pragma unroll
                    for (int r = 0; r < 4; r++)
                        outb[(size_t)(rowm + r) * 2304 + coln] = f2bf(v[r] + bv);
                } else {
                    int hh = (coln - 2 * EE) >> 6, d = (coln - 2 * EE) & 63;
                    int b = rowm >> 10, s = rowm & 1023;
                    ushort4 pk;
                    pk.x = f2bf(v[0] + bv); pk.y = f2bf(v[1] + bv);
                    pk.z = f2bf(v[2] + bv); pk.w = f2bf(v[3] + bv);
                    *(ushort4*)(vT + (((size_t)((b * HH + hh) * HD + d)) << 10) + s) = pk;
                }
            } else if (MODE == 1) {
#pragma unroll
                for (int r = 0; r < 4; r++) {
                    size_t idx = (size_t)(rowm + r) * N + coln;
                    hres[idx] += v[r] + bv;
                }
            } else {
#pragma unroll
                for (int r = 0; r < 4; r++) {
                    float x = v[r] + bv;
                    float t = x + 0.044715f * x * x * x;
                    float e = __expf(-1.5957691216057308f * t);  // exp(-2*sqrt(2/pi)*t)
                    float th = (1.f - e) / (1.f + e);
                    outb[(size_t)(rowm + r) * N + coln] = f2bf(0.5f * x * (1.f + th));
                }
            }
        }
    }
}

// ---------- flash attention ----------
// qkv: [B*S, 2304] bf16 (q cols 0..768, k cols 768..1536; v region garbage)
// vT:  [B, H, HD, S] bf16
// o:   [B*S, 768] bf16
// block = 256 threads = 4 waves; block covers one 32-row causal q-block for 2 heads.
__global__ __launch_bounds__(256) void attn_k(const u16* __restrict__ qkv,
                                              const u16* __restrict__ vT,
                                              u16* __restrict__ o) {
    __shared__ u16 P[4][16 * 40];  // per-wave P tile, pitch 40 (80B, 2-way-free)
    int tid = threadIdx.x, w = tid >> 6, lane = tid & 63;
    int quad = lane >> 4, l16 = lane & 15;
    int blk = blockIdx.x;
    int qb32 = blk & 31;
    int hp = (blk >> 5) % 6;
    int b = blk / 192;
    int hh = hp * 2 + (w >> 1);
    int q0 = qb32 * 32 + (w & 1) * 16;
    int kmax = (qb32 + 1) * 32;  // block-causal: allowed keys < kmax (uniform per block)

    const u16* qbase = qkv + (size_t)(b * SS + q0 + l16) * 2304 + hh * HD + quad * 8;
    bf16x8 qf0 = *(const bf16x8*)(qbase);
    bf16x8 qf1 = *(const bf16x8*)(qbase + 32);

    f32x4 of[4];
#pragma unroll
    for (int i = 0; i < 4; i++) of[i] = (f32x4){0.f, 0.f, 0.f, 0.f};
    float mrun[4], lrun[4];
#pragma unroll
    for (int r = 0; r < 4; r++) { mrun[r] = -__builtin_inff(); lrun[r] = 0.f; }

    const u16* kbase = qkv + (size_t)(b * SS + l16) * 2304 + EE + hh * HD + quad * 8;
    const u16* vbase = vT + (((size_t)((b * HH + hh) * HD + l16)) << 10) + quad * 8;
    u16* Pw = P[w];

    for (int kb = 0; kb < kmax; kb += 32) {
        const u16* kp = kbase + (size_t)kb * 2304;
        bf16x8 k00 = *(const bf16x8*)(kp);
        bf16x8 k01 = *(const bf16x8*)(kp + 32);
        bf16x8 k10 = *(const bf16x8*)(kp + 16 * 2304);
        bf16x8 k11 = *(const bf16x8*)(kp + 16 * 2304 + 32);
        f32x4 s0 = (f32x4){0.f, 0.f, 0.f, 0.f};
        f32x4 s1 = (f32x4){0.f, 0.f, 0.f, 0.f};
        s0 = __builtin_amdgcn_mfma_f32_16x16x32_bf16(qf0, k00, s0, 0, 0, 0);
        s0 = __builtin_amdgcn_mfma_f32_16x16x32_bf16(qf1, k01, s0, 0, 0, 0);
        s1 = __builtin_amdgcn_mfma_f32_16x16x32_bf16(qf0, k10, s1, 0, 0, 0);
        s1 = __builtin_amdgcn_mfma_f32_16x16x32_bf16(qf1, k11, s1, 0, 0, 0);

        float alpha[4];
#pragma unroll
        for (int r = 0; r < 4; r++) {
            float a0 = s0[r] * 0.125f, a1 = s1[r] * 0.125f;
            float mx = fmaxf(a0, a1);
#pragma unroll
            for (int m = 1; m < 16; m <<= 1) mx = fmaxf(mx, __shfl_xor(mx, m));
            float mnew = fmaxf(mrun[r], mx);
            alpha[r] = __expf(mrun[r] - mnew);
            float p0 = __expf(a0 - mnew);
            float p1 = __expf(a1 - mnew);
            float ps = p0 + p1;
#pragma unroll
            for (int m = 1; m < 16; m <<= 1) ps += __shfl_xor(ps, m);
            lrun[r] = lrun[r] * alpha[r] + ps;
            mrun[r] = mnew;
            Pw[(quad * 4 + r) * 40 + l16] = f2bf(p0);
            Pw[(quad * 4 + r) * 40 + 16 + l16] = f2bf(p1);
        }
#pragma unroll
        for (int n4 = 0; n4 < 4; n4++) {
            of[n4][0] *= alpha[0]; of[n4][1] *= alpha[1];
            of[n4][2] *= alpha[2]; of[n4][3] *= alpha[3];
        }
        __syncthreads();
        bf16x8 pf = *(const bf16x8*)(Pw + l16 * 40 + quad * 8);
        const u16* vp = vbase + kb;
#pragma unroll
        for (int n4 = 0; n4 < 4; n4++) {
            bf16x8 vf = *(const bf16x8*)(vp + ((size_t)(n4 * 16) << 10));
            of[n4] = __builtin_amdgcn_mfma_f32_16x16x32_bf16(pf, vf, of[n4], 0, 0, 0);
        }
        __syncthreads();
    }

    float inv[4];
#pragma unroll
    for (int r = 0; r < 4; r++) inv[r] = 1.f / lrun[r];
#pragma unroll
    for (int n4 = 0; n4 < 4; n4++)
#pragma unroll
        for (int r = 0; r < 4; r++)
            o[(size_t)(b * SS + q0 + quad * 4 + r) * EE + hh * HD + n4 * 16 + l16] =
                f2bf(of[n4][r] * inv[r]);
}

// ---------- launcher ----------
extern "C" void kernel_launch(void* const* d_in, const int* in_sizes, int n_in,
                              void* d_out, int out_size, void* d_ws, size_t ws_size,
                              hipStream_t stream) {
    const float* x     = (const float*)d_in[0];
    const int*   sd    = (const int*)d_in[1];
    const float* wpe   = (const float*)d_in[2];
    const float* ln1w  = (const float*)d_in[3];
    const float* ln1b  = (const float*)d_in[4];
    const float* in_w  = (const float*)d_in[5];
    const float* in_b  = (const float*)d_in[6];
    const float* out_w = (const float*)d_in[7];
    const float* out_b = (const float*)d_in[8];
    const float* ln2w  = (const float*)d_in[9];
    const float* ln2b  = (const float*)d_in[10];
    const float* fc_w  = (const float*)d_in[11];
    const float* fc_b  = (const float*)d_in[12];
    const float* pr_w  = (const float*)d_in[13];
    const float* pr_b  = (const float*)d_in[14];
    const float* lnfw  = (const float*)d_in[15];
    const float* lnfb  = (const float*)d_in[16];
    float* outp = (float*)d_out;

    char* ws = (char*)d_ws;
    float* h   = (float*)ws;                        // 25,165,824 B
    u16* ybuf  = (u16*)(ws + 25165824);             // 12,582,912 B
    u16* big   = (u16*)(ws + 37748736);             // 50,331,648 B (qkv / act)
    u16* vT    = (u16*)(ws + 88080384);             // 12,582,912 B
    u16* wb    = (u16*)(ws + 100663296);            // 56,623,104 B
    u16* w_in  = wb;                                // 4*2304*768
    u16* w_out = w_in + 7077888;                    // 4*768*768
    u16* w_fc  = w_out + 2359296;                   // 4*3072*768
    u16* w_pr  = w_fc + 9437184;                    // 4*768*3072

    cvt_k<<<1024, 256, 0, stream>>>(in_w,  w_in,  7077888 / 4);
    cvt_k<<<1024, 256, 0, stream>>>(out_w, w_out, 2359296 / 4);
    cvt_k<<<1024, 256, 0, stream>>>(fc_w,  w_fc,  9437184 / 4);
    cvt_k<<<1024, 256, 0, stream>>>(pr_w,  w_pr,  9437184 / 4);
    embed_k<<<6144, 256, 0, stream>>>(x, sd, wpe, h);

    for (int l = 0; l < LL; l++) {
        ln_k<true><<<2048, 256, 0, stream>>>(h, ln1w + l * EE, ln1b + l * EE, ybuf);
        gemm_bt<0><<<dim3(18, 64), 256, 0, stream>>>(
            ybuf, w_in + (size_t)l * 2304 * 768, in_b + l * 2304, nullptr, big, vT,
            8192, 2304, 768);
        attn_k<<<1536, 256, 0, stream>>>(big, vT, ybuf);
        gemm_bt<1><<<dim3(6, 64), 256, 0, stream>>>(
            ybuf, w_out + (size_t)l * 768 * 768, out_b + l * 768, h, nullptr, nullptr,
            8192, 768, 768);
        ln_k<true><<<2048, 256, 0, stream>>>(h, ln2w + l * EE, ln2b + l * EE, ybuf);
        gemm_bt<2><<<dim3(24, 64), 256, 0, stream>>>(
            ybuf, w_fc + (size_t)l * 3072 * 768, fc_b + l * 3072, nullptr, big, nullptr,
            8192, 3072, 768);
        gemm_bt<1><<<dim3(6, 64), 256, 0, stream>>>(
            big, w_pr + (size_t)l * 768 * 3072, pr_b + l * 768, h, nullptr, nullptr,
            8192, 768, 3072);
    }
    ln_k<false><<<2048, 256, 0, stream>>>(h, lnfw, lnfb, outp);
}

// Round 2
// 1529.227 us; speedup vs baseline: 1.3486x; 1.3486x over previous
//
#include <hip/hip_runtime.h>
#include <hip/hip_bf16.h>

// ---------- types ----------
typedef __attribute__((ext_vector_type(8))) __bf16 bf16x8;
typedef __attribute__((ext_vector_type(4))) float f32x4;

typedef unsigned short u16;

__device__ __forceinline__ u16 f2bf(float f) {
    unsigned int u = __float_as_uint(f);
    u += 0x7FFFu + ((u >> 16) & 1u);   // round-to-nearest-even
    return (u16)(u >> 16);
}

__device__ __forceinline__ void g2l16(const void* g, void* l) {
    __builtin_amdgcn_global_load_lds(
        (const __attribute__((address_space(1))) void*)g,
        (__attribute__((address_space(3))) void*)l, 16, 0, 0);
}

// ---------- constants ----------
#define BB 8
#define SS 1024
#define EE 768
#define HH 12
#define HD 64
#define LL 4

// ---------- fp32 -> bf16 convert ----------
__global__ __launch_bounds__(256) void cvt_k(const float* __restrict__ in,
                                             u16* __restrict__ out, int n4) {
    for (int i = blockIdx.x * 256 + threadIdx.x; i < n4; i += gridDim.x * 256) {
        float4 v = ((const float4*)in)[i];
        ushort4 u;
        u.x = f2bf(v.x); u.y = f2bf(v.y); u.z = f2bf(v.z); u.w = f2bf(v.w);
        ((ushort4*)out)[i] = u;
    }
}

// ---------- embed: h = x + wpe[study_date] ----------
__global__ __launch_bounds__(256) void embed_k(const float* __restrict__ x,
                                               const int* __restrict__ sd,
                                               const float* __restrict__ wpe,
                                               float* __restrict__ h) {
    int idx = blockIdx.x * 256 + threadIdx.x;          // over 8192*192 float4s
    int e4 = idx % 192;
    int bs = idx / 192;
    int b = bs >> 10;
    int t = (bs >> 5) & 31;
    int date = sd[b * 32 + t];
    date = date < 0 ? 0 : (date > 49 ? 49 : date);
    float4 xv = ((const float4*)x)[idx];
    float4 pv = ((const float4*)wpe)[date * 192 + e4];
    float4 r; r.x = xv.x + pv.x; r.y = xv.y + pv.y; r.z = xv.z + pv.z; r.w = xv.w + pv.w;
    ((float4*)h)[idx] = r;
}

// ---------- layernorm: wave per token ----------
template <bool BF16OUT>
__global__ __launch_bounds__(256) void ln_k(const float* __restrict__ in,
                                            const float* __restrict__ w,
                                            const float* __restrict__ b,
                                            void* __restrict__ out) {
    int tid = threadIdx.x, wv = tid >> 6, lane = tid & 63;
    int token = blockIdx.x * 4 + wv;
    const float4* ip = (const float4*)(in + (size_t)token * EE);
    float4 v[3];
#pragma unroll
    for (int p = 0; p < 3; p++) v[p] = ip[p * 64 + lane];
    float s = 0.f;
#pragma unroll
    for (int p = 0; p < 3; p++) s += v[p].x + v[p].y + v[p].z + v[p].w;
#pragma unroll
    for (int m = 1; m < 64; m <<= 1) s += __shfl_xor(s, m);
    float mean = s * (1.f / 768.f);
    float vs = 0.f;
#pragma unroll
    for (int p = 0; p < 3; p++) {
        float dx = v[p].x - mean, dy = v[p].y - mean, dz = v[p].z - mean, dw = v[p].w - mean;
        vs += dx * dx + dy * dy + dz * dz + dw * dw;
    }
#pragma unroll
    for (int m = 1; m < 64; m <<= 1) vs += __shfl_xor(vs, m);
    float rstd = rsqrtf(vs * (1.f / 768.f) + 1e-5f);
    const float4* wp = (const float4*)w;
    const float4* bp = (const float4*)b;
#pragma unroll
    for (int p = 0; p < 3; p++) {
        float4 wv4 = wp[p * 64 + lane], bv4 = bp[p * 64 + lane];
        float rx = (v[p].x - mean) * rstd * wv4.x + bv4.x;
        float ry = (v[p].y - mean) * rstd * wv4.y + bv4.y;
        float rz = (v[p].z - mean) * rstd * wv4.z + bv4.z;
        float rw = (v[p].w - mean) * rstd * wv4.w + bv4.w;
        if (BF16OUT) {
            ushort4 u; u.x = f2bf(rx); u.y = f2bf(ry); u.z = f2bf(rz); u.w = f2bf(rw);
            ((ushort4*)((u16*)out + (size_t)token * EE))[p * 64 + lane] = u;
        } else {
            float4 r; r.x = rx; r.y = ry; r.z = rz; r.w = rw;
            ((float4*)((float*)out + (size_t)token * EE))[p * 64 + lane] = r;
        }
    }
}

// ---------- GEMM: C[M,N] = A[M,K](bf16) * Bw[N,K]^T(bf16) + bias ----------
// MODE 0: QKV epilogue  (q -> qT [B,H,S,HD]; k -> kT [B,H,S,HD]; v -> vT [B,H,HD,S])
// MODE 1: residual      (hres[M,N] += C + bias)
// MODE 2: NewGELU       (outb[M,N] = bf16(gelu(C + bias)))
template <int MODE>
__global__ __launch_bounds__(256) void gemm_bt(const u16* __restrict__ A,
                                               const u16* __restrict__ Bw,
                                               const float* __restrict__ bias,
                                               float* __restrict__ hres,
                                               u16* __restrict__ outb,
                                               u16* __restrict__ vT,
                                               u16* __restrict__ kT,
                                               int M, int N, int K) {
    __shared__ u16 As[4096];  // 128 rows x 32 cols, 16B-chunk swizzled
    __shared__ u16 Bs[4096];
    const int tid = threadIdx.x;
    const int lane = tid & 63, w = tid >> 6;
    const int quad = lane >> 4, l16 = lane & 15;
    const int m0 = blockIdx.y * 128, n0 = blockIdx.x * 128;
    const int wm = (w >> 1) * 64, wn = (w & 1) * 64;

    f32x4 acc[4][4];
#pragma unroll
    for (int i = 0; i < 4; i++)
#pragma unroll
        for (int j = 0; j < 4; j++) acc[i][j] = (f32x4){0.f, 0.f, 0.f, 0.f};

    // staging: chunk c holds A[m0 + (c>>2)][kb + 8*((c&3)^((c>>3)&3)) .. +8)
    const int c0 = w * 128 + lane;
    const int c1 = c0 + 64;
    const int rA0 = c0 >> 2, g0 = (((c0 & 3) ^ ((c0 >> 3) & 3)) * 8);
    const int rA1 = c1 >> 2, g1 = (((c1 & 3) ^ ((c1 >> 3) & 3)) * 8);
    const u16* Ap0 = A + (size_t)(m0 + rA0) * K + g0;
    const u16* Ap1 = A + (size_t)(m0 + rA1) * K + g1;
    const u16* Bp0 = Bw + (size_t)(n0 + rA0) * K + g0;
    const u16* Bp1 = Bw + (size_t)(n0 + rA1) * K + g1;
    char* lA0 = (char*)As + (w * 128) * 16;
    char* lA1 = (char*)As + (w * 128 + 64) * 16;
    char* lB0 = (char*)Bs + (w * 128) * 16;
    char* lB1 = (char*)Bs + (w * 128 + 64) * 16;

    const int swz = (quad ^ ((l16 >> 1) & 3)) * 8;

    for (int kb = 0; kb < K; kb += 32) {
        g2l16(Ap0 + kb, lA0);
        g2l16(Ap1 + kb, lA1);
        g2l16(Bp0 + kb, lB0);
        g2l16(Bp1 + kb, lB1);
        __syncthreads();
        bf16x8 af[4], bfr[4];
#pragma unroll
        for (int t = 0; t < 4; t++) {
            int rowA = wm + t * 16 + l16;
            af[t] = *(const bf16x8*)(As + rowA * 32 + swz);
            int rowB = wn + t * 16 + l16;
            bfr[t] = *(const bf16x8*)(Bs + rowB * 32 + swz);
        }
#pragma unroll
        for (int tm = 0; tm < 4; tm++)
#pragma unroll
            for (int tn = 0; tn < 4; tn++)
                acc[tm][tn] = __builtin_amdgcn_mfma_f32_16x16x32_bf16(
                    af[tm], bfr[tn], acc[tm][tn], 0, 0, 0);
        __syncthreads();
    }

    // epilogue: C row = m0+wm+tm*16+quad*4+r ; col = n0+wn+tn*16+l16
#pragma unroll
    for (int tm = 0; tm < 4; tm++) {
        int rowm = m0 + wm + tm * 16 + quad * 4;
#pragma unroll
        for (int tn = 0; tn < 4; tn++) {
            int coln = n0 + wn + tn * 16 + l16;
            float bv = bias[coln];
            f32x4 v = acc[tm][tn];
            if (MODE == 0) {
                int b = rowm >> 10, s = rowm & 1023;
                if (coln < EE) {
                    int hh = coln >> 6, d = coln & 63;
                    u16* qp = outb + ((size_t)(b * HH + hh) * SS + s) * HD + d;
#pragma unroll
                    for (int r = 0; r < 4; r++) qp[r * HD] = f2bf(v[r] + bv);
                } else if (coln < 2 * EE) {
                    int hh = (coln - EE) >> 6, d = (coln - EE) & 63;
                    u16* kp = kT + ((size_t)(b * HH + hh) * SS + s) * HD + d;
#pragma unroll
                    for (int r = 0; r < 4; r++) kp[r * HD] = f2bf(v[r] + bv);
                } else {
                    int hh = (coln - 2 * EE) >> 6, d = (coln - 2 * EE) & 63;
                    ushort4 pk;
                    pk.x = f2bf(v[0] + bv); pk.y = f2bf(v[1] + bv);
                    pk.z = f2bf(v[2] + bv); pk.w = f2bf(v[3] + bv);
                    *(ushort4*)(vT + (((size_t)((b * HH + hh) * HD + d)) << 10) + s) = pk;
                }
            } else if (MODE == 1) {
#pragma unroll
                for (int r = 0; r < 4; r++) {
                    size_t idx = (size_t)(rowm + r) * N + coln;
                    hres[idx] += v[r] + bv;
                }
            } else {
#pragma unroll
                for (int r = 0; r < 4; r++) {
                    float x = v[r] + bv;
                    float t = x + 0.044715f * x * x * x;
                    float e = __expf(-1.5957691216057308f * t);  // exp(-2*sqrt(2/pi)*t)
                    float th = (1.f - e) / (1.f + e);
                    outb[(size_t)(rowm + r) * N + coln] = f2bf(0.5f * x * (1.f + th));
                }
            }
        }
    }
}

// ---------- flash attention ----------
// qT,kT: [B,H,S,HD] bf16   vT: [B,H,HD,S] bf16   o: [B*S, 768] bf16
// block = 4 waves = one (b, head, 64 q-rows); K/V tiles staged in LDS, shared by all waves.
// Block-causal: waves 0,1 (rows q0..q0+31) see keys < q0+32; waves 2,3 see < q0+64.
__global__ __launch_bounds__(256) void attn_k(const u16* __restrict__ qT,
                                              const u16* __restrict__ kT,
                                              const u16* __restrict__ vT,
                                              u16* __restrict__ o) {
    __shared__ u16 Ks[2048];        // 32 tokens x 64 d, 16B chunks swizzled
    __shared__ u16 Vs[2048];        // 64 d x 32 tokens, 16B chunks swizzled
    __shared__ u16 P[4][16 * 40];   // per-wave P tile
    int tid = threadIdx.x, w = tid >> 6, lane = tid & 63;
    int quad = lane >> 4, l16 = lane & 15;
    int blk = blockIdx.x;
    int qg = 15 - (blk / 96);       // largest q-groups dispatch first (load balance)
    int bh = blk % 96;              // b*12 + h
    int b = bh / HH, hh = bh % HH;
    int q0 = qg * 64;
    int kend_blk = q0 + 64;
    int kend_w = q0 + ((w >> 1) ? 64 : 32);

    const u16* qbase = qT + ((size_t)bh * SS + q0 + w * 16 + l16) * HD + quad * 8;
    bf16x8 qf0 = *(const bf16x8*)(qbase);
    bf16x8 qf1 = *(const bf16x8*)(qbase + 32);

    f32x4 of[4];
#pragma unroll
    for (int i = 0; i < 4; i++) of[i] = (f32x4){0.f, 0.f, 0.f, 0.f};
    float mrun[4], lrun[4];
#pragma unroll
    for (int r = 0; r < 4; r++) { mrun[r] = -__builtin_inff(); lrun[r] = 0.f; }

    // staging addresses: slot s (=tid) of Ks holds K[token=s>>3][dchunk=(s&7)^(token&7)]
    int tK = tid >> 3, dcK = ((tid & 7) ^ (tK & 7));
    const u16* kg = kT + ((size_t)bh * SS + tK) * HD + dcK * 8;
    char* kl = (char*)Ks + w * 1024;
    // slot s of Vs holds V[d=s>>2][tokchunk=(s&3)^((d>>1)&3)]
    int dV = tid >> 2, tcV = ((tid & 3) ^ ((dV >> 1) & 3));
    const u16* vg = vT + ((size_t)bh * HD + dV) * SS + tcV * 8;
    char* vl = (char*)Vs + w * 1024;
    u16* Pw = P[w];

    for (int kb = 0; kb < kend_blk; kb += 32) {
        g2l16(kg + (size_t)kb * HD, kl);
        g2l16(vg + kb, vl);
        __syncthreads();
        if (kb < kend_w) {
            int t0 = l16, t1 = 16 + l16;
            bf16x8 k00 = *(const bf16x8*)(Ks + (t0 * 8 + (quad ^ (l16 & 7))) * 8);
            bf16x8 k01 = *(const bf16x8*)(Ks + (t0 * 8 + ((4 + quad) ^ (l16 & 7))) * 8);
            bf16x8 k10 = *(const bf16x8*)(Ks + (t1 * 8 + (quad ^ (l16 & 7))) * 8);
            bf16x8 k11 = *(const bf16x8*)(Ks + (t1 * 8 + ((4 + quad) ^ (l16 & 7))) * 8);
            f32x4 s0 = (f32x4){0.f, 0.f, 0.f, 0.f};
            f32x4 s1 = (f32x4){0.f, 0.f, 0.f, 0.f};
            s0 = __builtin_amdgcn_mfma_f32_16x16x32_bf16(qf0, k00, s0, 0, 0, 0);
            s0 = __builtin_amdgcn_mfma_f32_16x16x32_bf16(qf1, k01, s0, 0, 0, 0);
            s1 = __builtin_amdgcn_mfma_f32_16x16x32_bf16(qf0, k10, s1, 0, 0, 0);
            s1 = __builtin_amdgcn_mfma_f32_16x16x32_bf16(qf1, k11, s1, 0, 0, 0);

            float alpha[4];
#pragma unroll
            for (int r = 0; r < 4; r++) {
                float a0 = s0[r] * 0.125f, a1 = s1[r] * 0.125f;
                float mx = fmaxf(a0, a1);
#pragma unroll
                for (int m = 1; m < 16; m <<= 1) mx = fmaxf(mx, __shfl_xor(mx, m));
                float mnew = fmaxf(mrun[r], mx);
                alpha[r] = __expf(mrun[r] - mnew);
                float p0 = __expf(a0 - mnew);
                float p1 = __expf(a1 - mnew);
                float ps = p0 + p1;
#pragma unroll
                for (int m = 1; m < 16; m <<= 1) ps += __shfl_xor(ps, m);
                lrun[r] = lrun[r] * alpha[r] + ps;
                mrun[r] = mnew;
                Pw[(quad * 4 + r) * 40 + l16] = f2bf(p0);
                Pw[(quad * 4 + r) * 40 + 16 + l16] = f2bf(p1);
            }
#pragma unroll
            for (int n4 = 0; n4 < 4; n4++) {
                of[n4][0] *= alpha[0]; of[n4][1] *= alpha[1];
                of[n4][2] *= alpha[2]; of[n4][3] *= alpha[3];
            }
            // P round-trip is per-wave: only lgkmcnt ordering needed, no barrier
            bf16x8 pf = *(const bf16x8*)(Pw + l16 * 40 + quad * 8);
#pragma unroll
            for (int n4 = 0; n4 < 4; n4++) {
                int d = n4 * 16 + l16;
                bf16x8 vf = *(const bf16x8*)(Vs + (d * 4 + (quad ^ ((d >> 1) & 3))) * 8);
                of[n4] = __builtin_amdgcn_mfma_f32_16x16x32_bf16(pf, vf, of[n4], 0, 0, 0);
            }
        }
        __syncthreads();
    }

    float inv[4];
#pragma unroll
    for (int r = 0; r < 4; r++) inv[r] = 1.f / lrun[r];
#pragma unroll
    for (int n4 = 0; n4 < 4; n4++)
#pragma unroll
        for (int r = 0; r < 4; r++)
            o[(size_t)(b * SS + q0 + w * 16 + quad * 4 + r) * EE + hh * HD + n4 * 16 + l16] =
                f2bf(of[n4][r] * inv[r]);
}

// ---------- launcher ----------
extern "C" void kernel_launch(void* const* d_in, const int* in_sizes, int n_in,
                              void* d_out, int out_size, void* d_ws, size_t ws_size,
                              hipStream_t stream) {
    const float* x     = (const float*)d_in[0];
    const int*   sd    = (const int*)d_in[1];
    const float* wpe   = (const float*)d_in[2];
    const float* ln1w  = (const float*)d_in[3];
    const float* ln1b  = (const float*)d_in[4];
    const float* in_w  = (const float*)d_in[5];
    const float* in_b  = (const float*)d_in[6];
    const float* out_w = (const float*)d_in[7];
    const float* out_b = (const float*)d_in[8];
    const float* ln2w  = (const float*)d_in[9];
    const float* ln2b  = (const float*)d_in[10];
    const float* fc_w  = (const float*)d_in[11];
    const float* fc_b  = (const float*)d_in[12];
    const float* pr_w  = (const float*)d_in[13];
    const float* pr_b  = (const float*)d_in[14];
    const float* lnfw  = (const float*)d_in[15];
    const float* lnfb  = (const float*)d_in[16];
    float* outp = (float*)d_out;

    char* ws = (char*)d_ws;
    float* h   = (float*)ws;                        // 25,165,824 B
    u16* ybuf  = (u16*)(ws + 25165824);             // 12,582,912 B
    u16* big   = (u16*)(ws + 37748736);             // 50,331,648 B (qT+kT / fc act)
    u16* qT    = big;                               // 6,291,456 elems
    u16* kT    = big + 6291456;                     // 6,291,456 elems
    u16* vT    = (u16*)(ws + 88080384);             // 12,582,912 B
    u16* wb    = (u16*)(ws + 100663296);            // 56,623,104 B
    u16* w_in  = wb;                                // 4*2304*768
    u16* w_out = w_in + 7077888;                    // 4*768*768
    u16* w_fc  = w_out + 2359296;                   // 4*3072*768
    u16* w_pr  = w_fc + 9437184;                    // 4*768*3072

    cvt_k<<<1024, 256, 0, stream>>>(in_w,  w_in,  7077888 / 4);
    cvt_k<<<1024, 256, 0, stream>>>(out_w, w_out, 2359296 / 4);
    cvt_k<<<1024, 256, 0, stream>>>(fc_w,  w_fc,  9437184 / 4);
    cvt_k<<<1024, 256, 0, stream>>>(pr_w,  w_pr,  9437184 / 4);
    embed_k<<<6144, 256, 0, stream>>>(x, sd, wpe, h);

    for (int l = 0; l < LL; l++) {
        ln_k<true><<<2048, 256, 0, stream>>>(h, ln1w + l * EE, ln1b + l * EE, ybuf);
        gemm_bt<0><<<dim3(18, 64), 256, 0, stream>>>(
            ybuf, w_in + (size_t)l * 2304 * 768, in_b + l * 2304, nullptr, qT, vT, kT,
            8192, 2304, 768);
        attn_k<<<1536, 256, 0, stream>>>(qT, kT, vT, ybuf);
        gemm_bt<1><<<dim3(6, 64), 256, 0, stream>>>(
            ybuf, w_out + (size_t)l * 768 * 768, out_b + l * 768, h, nullptr, nullptr, nullptr,
            8192, 768, 768);
        ln_k<true><<<2048, 256, 0, stream>>>(h, ln2w + l * EE, ln2b + l * EE, ybuf);
        gemm_bt<2><<<dim3(24, 64), 256, 0, stream>>>(
            ybuf, w_fc + (size_t)l * 3072 * 768, fc_b + l * 3072, nullptr, big, nullptr, nullptr,
            8192, 3072, 768);
        gemm_bt<1><<<dim3(6, 64), 256, 0, stream>>>(
            big, w_pr + (size_t)l * 768 * 3072, pr_b + l * 768, h, nullptr, nullptr, nullptr,
            8192, 768, 3072);
    }
    ln_k<false><<<2048, 256, 0, stream>>>(h, lnfw, lnfb, outp);
}

// Round 3
// 1397.433 us; speedup vs baseline: 1.4758x; 1.0943x over previous
//
#include <hip/hip_runtime.h>
#include <hip/hip_bf16.h>

// ---------- types ----------
typedef __attribute__((ext_vector_type(8))) __bf16 bf16x8;
typedef __attribute__((ext_vector_type(4))) float f32x4;

typedef unsigned short u16;

__device__ __forceinline__ u16 f2bf(float f) {
    unsigned int u = __float_as_uint(f);
    u += 0x7FFFu + ((u >> 16) & 1u);   // round-to-nearest-even
    return (u16)(u >> 16);
}

__device__ __forceinline__ void g2l16(const void* g, void* l) {
    __builtin_amdgcn_global_load_lds(
        (const __attribute__((address_space(1))) void*)g,
        (__attribute__((address_space(3))) void*)l, 16, 0, 0);
}

// ---------- constants ----------
#define BB 8
#define SS 1024
#define EE 768
#define HH 12
#define HD 64
#define LL 4

// ---------- fp32 -> bf16 convert ----------
__global__ __launch_bounds__(256) void cvt_k(const float* __restrict__ in,
                                             u16* __restrict__ out, int n4) {
    for (int i = blockIdx.x * 256 + threadIdx.x; i < n4; i += gridDim.x * 256) {
        float4 v = ((const float4*)in)[i];
        ushort4 u;
        u.x = f2bf(v.x); u.y = f2bf(v.y); u.z = f2bf(v.z); u.w = f2bf(v.w);
        ((ushort4*)out)[i] = u;
    }
}

// ---------- embed: h = x + wpe[study_date] ----------
__global__ __launch_bounds__(256) void embed_k(const float* __restrict__ x,
                                               const int* __restrict__ sd,
                                               const float* __restrict__ wpe,
                                               float* __restrict__ h) {
    int idx = blockIdx.x * 256 + threadIdx.x;          // over 8192*192 float4s
    int e4 = idx % 192;
    int bs = idx / 192;
    int b = bs >> 10;
    int t = (bs >> 5) & 31;
    int date = sd[b * 32 + t];
    date = date < 0 ? 0 : (date > 49 ? 49 : date);
    float4 xv = ((const float4*)x)[idx];
    float4 pv = ((const float4*)wpe)[date * 192 + e4];
    float4 r; r.x = xv.x + pv.x; r.y = xv.y + pv.y; r.z = xv.z + pv.z; r.w = xv.w + pv.w;
    ((float4*)h)[idx] = r;
}

// ---------- layernorm: wave per token ----------
template <bool BF16OUT>
__global__ __launch_bounds__(256) void ln_k(const float* __restrict__ in,
                                            const float* __restrict__ w,
                                            const float* __restrict__ b,
                                            void* __restrict__ out) {
    int tid = threadIdx.x, wv = tid >> 6, lane = tid & 63;
    int token = blockIdx.x * 4 + wv;
    const float4* ip = (const float4*)(in + (size_t)token * EE);
    float4 v[3];
#pragma unroll
    for (int p = 0; p < 3; p++) v[p] = ip[p * 64 + lane];
    float s = 0.f;
#pragma unroll
    for (int p = 0; p < 3; p++) s += v[p].x + v[p].y + v[p].z + v[p].w;
#pragma unroll
    for (int m = 1; m < 64; m <<= 1) s += __shfl_xor(s, m);
    float mean = s * (1.f / 768.f);
    float vs = 0.f;
#pragma unroll
    for (int p = 0; p < 3; p++) {
        float dx = v[p].x - mean, dy = v[p].y - mean, dz = v[p].z - mean, dw = v[p].w - mean;
        vs += dx * dx + dy * dy + dz * dz + dw * dw;
    }
#pragma unroll
    for (int m = 1; m < 64; m <<= 1) vs += __shfl_xor(vs, m);
    float rstd = rsqrtf(vs * (1.f / 768.f) + 1e-5f);
    const float4* wp = (const float4*)w;
    const float4* bp = (const float4*)b;
#pragma unroll
    for (int p = 0; p < 3; p++) {
        float4 wv4 = wp[p * 64 + lane], bv4 = bp[p * 64 + lane];
        float rx = (v[p].x - mean) * rstd * wv4.x + bv4.x;
        float ry = (v[p].y - mean) * rstd * wv4.y + bv4.y;
        float rz = (v[p].z - mean) * rstd * wv4.z + bv4.z;
        float rw = (v[p].w - mean) * rstd * wv4.w + bv4.w;
        if (BF16OUT) {
            ushort4 u; u.x = f2bf(rx); u.y = f2bf(ry); u.z = f2bf(rz); u.w = f2bf(rw);
            ((ushort4*)((u16*)out + (size_t)token * EE))[p * 64 + lane] = u;
        } else {
            float4 r; r.x = rx; r.y = ry; r.z = rz; r.w = rw;
            ((float4*)((float*)out + (size_t)token * EE))[p * 64 + lane] = r;
        }
    }
}

// ---------- GEMM: C[M,N] = A[M,K](bf16) * Bw[N,K]^T(bf16) + bias ----------
// 1-D grid of (N/128)*(M/128) blocks; id%8 = XCD owns a contiguous 8-M-tile
// band, walking N fastest (L2 locality: A band ~1.6-6 MB resident, B streamed).
// LDS double-buffered, ONE barrier per K-iter: stage(k+1) issues overlap
// compute(k); the vmcnt(0) drain at the next barrier finds loads landed.
// MODE 0: QKV epilogue  (q -> qT [B,H,S,HD]; k -> kT [B,H,S,HD]; v -> vT [B,H,HD,S])
// MODE 1: residual      (hres[M,N] += C + bias)
// MODE 2: NewGELU       (outb[M,N] = bf16(gelu(C + bias)))
template <int MODE>
__global__ __launch_bounds__(256) void gemm_bt(const u16* __restrict__ A,
                                               const u16* __restrict__ Bw,
                                               const float* __restrict__ bias,
                                               float* __restrict__ hres,
                                               u16* __restrict__ outb,
                                               u16* __restrict__ vT,
                                               u16* __restrict__ kT,
                                               int M, int N, int K) {
    __shared__ u16 As[2][4096];  // 128 rows x 32 cols, 16B-chunk swizzled, x2 buf
    __shared__ u16 Bs[2][4096];
    const int tid = threadIdx.x;
    const int lane = tid & 63, w = tid >> 6;
    const int quad = lane >> 4, l16 = lane & 15;

    // XCD-aware block remap (ny = M/128 = 64 always)
    const int nx = N >> 7;
    const int id = blockIdx.x;
    const int xcd = id & 7, s = id >> 3;
    const int yt = xcd * 8 + s / nx;
    const int xt = s % nx;
    const int m0 = yt * 128, n0 = xt * 128;
    const int wm = (w >> 1) * 64, wn = (w & 1) * 64;

    f32x4 acc[4][4];
#pragma unroll
    for (int i = 0; i < 4; i++)
#pragma unroll
        for (int j = 0; j < 4; j++) acc[i][j] = (f32x4){0.f, 0.f, 0.f, 0.f};

    // staging: chunk c holds A[m0 + (c>>2)][kb + 8*((c&3)^((c>>3)&3)) .. +8)
    const int c0 = w * 128 + lane;
    const int c1 = c0 + 64;
    const int rA0 = c0 >> 2, g0 = (((c0 & 3) ^ ((c0 >> 3) & 3)) * 8);
    const int rA1 = c1 >> 2, g1 = (((c1 & 3) ^ ((c1 >> 3) & 3)) * 8);
    const u16* Ap0 = A + (size_t)(m0 + rA0) * K + g0;
    const u16* Ap1 = A + (size_t)(m0 + rA1) * K + g1;
    const u16* Bp0 = Bw + (size_t)(n0 + rA0) * K + g0;
    const u16* Bp1 = Bw + (size_t)(n0 + rA1) * K + g1;
    char* lA0 = (char*)As + (w * 128) * 16;
    char* lA1 = (char*)As + (w * 128 + 64) * 16;
    char* lB0 = (char*)Bs + (w * 128) * 16;
    char* lB1 = (char*)Bs + (w * 128 + 64) * 16;

    const int swz = (quad ^ ((l16 >> 1) & 3)) * 8;

    const int nk = K >> 5;
    // prologue: stage tile 0 into buffer 0
    g2l16(Ap0, lA0); g2l16(Ap1, lA1); g2l16(Bp0, lB0); g2l16(Bp1, lB1);

    for (int ki = 0; ki < nk; ki++) {
        __syncthreads();  // tile ki ready; buffer ki^1 free (reads done pre-barrier)
        if (ki + 1 < nk) {
            const int kb = (ki + 1) << 5;
            const int bo = ((ki + 1) & 1) * 8192;
            g2l16(Ap0 + kb, lA0 + bo);
            g2l16(Ap1 + kb, lA1 + bo);
            g2l16(Bp0 + kb, lB0 + bo);
            g2l16(Bp1 + kb, lB1 + bo);
        }
        const u16* Ab = (const u16*)As + (ki & 1) * 4096;
        const u16* Bb = (const u16*)Bs + (ki & 1) * 4096;
        bf16x8 af[4], bfr[4];
#pragma unroll
        for (int t = 0; t < 4; t++) {
            int rowA = wm + t * 16 + l16;
            af[t] = *(const bf16x8*)(Ab + rowA * 32 + swz);
            int rowB = wn + t * 16 + l16;
            bfr[t] = *(const bf16x8*)(Bb + rowB * 32 + swz);
        }
#pragma unroll
        for (int tm = 0; tm < 4; tm++)
#pragma unroll
            for (int tn = 0; tn < 4; tn++)
                acc[tm][tn] = __builtin_amdgcn_mfma_f32_16x16x32_bf16(
                    af[tm], bfr[tn], acc[tm][tn], 0, 0, 0);
    }

    // epilogue: C row = m0+wm+tm*16+quad*4+r ; col = n0+wn+tn*16+l16
#pragma unroll
    for (int tm = 0; tm < 4; tm++) {
        int rowm = m0 + wm + tm * 16 + quad * 4;
#pragma unroll
        for (int tn = 0; tn < 4; tn++) {
            int coln = n0 + wn + tn * 16 + l16;
            float bv = bias[coln];
            f32x4 v = acc[tm][tn];
            if (MODE == 0) {
                int b = rowm >> 10, s2 = rowm & 1023;
                if (coln < EE) {
                    int hh = coln >> 6, d = coln & 63;
                    u16* qp = outb + ((size_t)(b * HH + hh) * SS + s2) * HD + d;
#pragma unroll
                    for (int r = 0; r < 4; r++) qp[r * HD] = f2bf(v[r] + bv);
                } else if (coln < 2 * EE) {
                    int hh = (coln - EE) >> 6, d = (coln - EE) & 63;
                    u16* kp = kT + ((size_t)(b * HH + hh) * SS + s2) * HD + d;
#pragma unroll
                    for (int r = 0; r < 4; r++) kp[r * HD] = f2bf(v[r] + bv);
                } else {
                    int hh = (coln - 2 * EE) >> 6, d = (coln - 2 * EE) & 63;
                    ushort4 pk;
                    pk.x = f2bf(v[0] + bv); pk.y = f2bf(v[1] + bv);
                    pk.z = f2bf(v[2] + bv); pk.w = f2bf(v[3] + bv);
                    *(ushort4*)(vT + (((size_t)((b * HH + hh) * HD + d)) << 10) + s2) = pk;
                }
            } else if (MODE == 1) {
#pragma unroll
                for (int r = 0; r < 4; r++) {
                    size_t idx = (size_t)(rowm + r) * N + coln;
                    hres[idx] += v[r] + bv;
                }
            } else {
#pragma unroll
                for (int r = 0; r < 4; r++) {
                    float x = v[r] + bv;
                    float t = x + 0.044715f * x * x * x;
                    float e = __expf(-1.5957691216057308f * t);  // exp(-2*sqrt(2/pi)*t)
                    float th = (1.f - e) / (1.f + e);
                    outb[(size_t)(rowm + r) * N + coln] = f2bf(0.5f * x * (1.f + th));
                }
            }
        }
    }
}

// ---------- flash attention ----------
// qT,kT: [B,H,S,HD] bf16   vT: [B,H,HD,S] bf16   o: [B*S, 768] bf16
// block = 4 waves = one (b, head, 64 q-rows); K/V tiles staged in LDS, shared by all waves.
// Block-causal: waves 0,1 (rows q0..q0+31) see keys < q0+32; waves 2,3 see < q0+64.
__global__ __launch_bounds__(256) void attn_k(const u16* __restrict__ qT,
                                              const u16* __restrict__ kT,
                                              const u16* __restrict__ vT,
                                              u16* __restrict__ o) {
    __shared__ u16 Ks[2048];        // 32 tokens x 64 d, 16B chunks swizzled
    __shared__ u16 Vs[2048];        // 64 d x 32 tokens, 16B chunks swizzled
    __shared__ u16 P[4][16 * 40];   // per-wave P tile
    int tid = threadIdx.x, w = tid >> 6, lane = tid & 63;
    int quad = lane >> 4, l16 = lane & 15;
    int blk = blockIdx.x;
    int qg = 15 - (blk / 96);       // largest q-groups dispatch first (load balance)
    int bh = blk % 96;              // b*12 + h
    int b = bh / HH, hh = bh % HH;
    int q0 = qg * 64;
    int kend_blk = q0 + 64;
    int kend_w = q0 + ((w >> 1) ? 64 : 32);

    const u16* qbase = qT + ((size_t)bh * SS + q0 + w * 16 + l16) * HD + quad * 8;
    bf16x8 qf0 = *(const bf16x8*)(qbase);
    bf16x8 qf1 = *(const bf16x8*)(qbase + 32);

    f32x4 of[4];
#pragma unroll
    for (int i = 0; i < 4; i++) of[i] = (f32x4){0.f, 0.f, 0.f, 0.f};
    float mrun[4], lrun[4];
#pragma unroll
    for (int r = 0; r < 4; r++) { mrun[r] = -__builtin_inff(); lrun[r] = 0.f; }

    // staging addresses: slot s (=tid) of Ks holds K[token=s>>3][dchunk=(s&7)^(token&7)]
    int tK = tid >> 3, dcK = ((tid & 7) ^ (tK & 7));
    const u16* kg = kT + ((size_t)bh * SS + tK) * HD + dcK * 8;
    char* kl = (char*)Ks + w * 1024;
    // slot s of Vs holds V[d=s>>2][tokchunk=(s&3)^((d>>1)&3)]
    int dV = tid >> 2, tcV = ((tid & 3) ^ ((dV >> 1) & 3));
    const u16* vg = vT + ((size_t)bh * HD + dV) * SS + tcV * 8;
    char* vl = (char*)Vs + w * 1024;
    u16* Pw = P[w];

    for (int kb = 0; kb < kend_blk; kb += 32) {
        g2l16(kg + (size_t)kb * HD, kl);
        g2l16(vg + kb, vl);
        __syncthreads();
        if (kb < kend_w) {
            int t0 = l16, t1 = 16 + l16;
            bf16x8 k00 = *(const bf16x8*)(Ks + (t0 * 8 + (quad ^ (l16 & 7))) * 8);
            bf16x8 k01 = *(const bf16x8*)(Ks + (t0 * 8 + ((4 + quad) ^ (l16 & 7))) * 8);
            bf16x8 k10 = *(const bf16x8*)(Ks + (t1 * 8 + (quad ^ (l16 & 7))) * 8);
            bf16x8 k11 = *(const bf16x8*)(Ks + (t1 * 8 + ((4 + quad) ^ (l16 & 7))) * 8);
            f32x4 s0 = (f32x4){0.f, 0.f, 0.f, 0.f};
            f32x4 s1 = (f32x4){0.f, 0.f, 0.f, 0.f};
            s0 = __builtin_amdgcn_mfma_f32_16x16x32_bf16(qf0, k00, s0, 0, 0, 0);
            s0 = __builtin_amdgcn_mfma_f32_16x16x32_bf16(qf1, k01, s0, 0, 0, 0);
            s1 = __builtin_amdgcn_mfma_f32_16x16x32_bf16(qf0, k10, s1, 0, 0, 0);
            s1 = __builtin_amdgcn_mfma_f32_16x16x32_bf16(qf1, k11, s1, 0, 0, 0);

            float alpha[4];
#pragma unroll
            for (int r = 0; r < 4; r++) {
                float a0 = s0[r] * 0.125f, a1 = s1[r] * 0.125f;
                float mx = fmaxf(a0, a1);
#pragma unroll
                for (int m = 1; m < 16; m <<= 1) mx = fmaxf(mx, __shfl_xor(mx, m));
                float mnew = fmaxf(mrun[r], mx);
                alpha[r] = __expf(mrun[r] - mnew);
                float p0 = __expf(a0 - mnew);
                float p1 = __expf(a1 - mnew);
                float ps = p0 + p1;
#pragma unroll
                for (int m = 1; m < 16; m <<= 1) ps += __shfl_xor(ps, m);
                lrun[r] = lrun[r] * alpha[r] + ps;
                mrun[r] = mnew;
                Pw[(quad * 4 + r) * 40 + l16] = f2bf(p0);
                Pw[(quad * 4 + r) * 40 + 16 + l16] = f2bf(p1);
            }
#pragma unroll
            for (int n4 = 0; n4 < 4; n4++) {
                of[n4][0] *= alpha[0]; of[n4][1] *= alpha[1];
                of[n4][2] *= alpha[2]; of[n4][3] *= alpha[3];
            }
            // P round-trip is per-wave: only lgkmcnt ordering needed, no barrier
            bf16x8 pf = *(const bf16x8*)(Pw + l16 * 40 + quad * 8);
#pragma unroll
            for (int n4 = 0; n4 < 4; n4++) {
                int d = n4 * 16 + l16;
                bf16x8 vf = *(const bf16x8*)(Vs + (d * 4 + (quad ^ ((d >> 1) & 3))) * 8);
                of[n4] = __builtin_amdgcn_mfma_f32_16x16x32_bf16(pf, vf, of[n4], 0, 0, 0);
            }
        }
        __syncthreads();
    }

    float inv[4];
#pragma unroll
    for (int r = 0; r < 4; r++) inv[r] = 1.f / lrun[r];
#pragma unroll
    for (int n4 = 0; n4 < 4; n4++)
#pragma unroll
        for (int r = 0; r < 4; r++)
            o[(size_t)(b * SS + q0 + w * 16 + quad * 4 + r) * EE + hh * HD + n4 * 16 + l16] =
                f2bf(of[n4][r] * inv[r]);
}

// ---------- launcher ----------
extern "C" void kernel_launch(void* const* d_in, const int* in_sizes, int n_in,
                              void* d_out, int out_size, void* d_ws, size_t ws_size,
                              hipStream_t stream) {
    const float* x     = (const float*)d_in[0];
    const int*   sd    = (const int*)d_in[1];
    const float* wpe   = (const float*)d_in[2];
    const float* ln1w  = (const float*)d_in[3];
    const float* ln1b  = (const float*)d_in[4];
    const float* in_w  = (const float*)d_in[5];
    const float* in_b  = (const float*)d_in[6];
    const float* out_w = (const float*)d_in[7];
    const float* out_b = (const float*)d_in[8];
    const float* ln2w  = (const float*)d_in[9];
    const float* ln2b  = (const float*)d_in[10];
    const float* fc_w  = (const float*)d_in[11];
    const float* fc_b  = (const float*)d_in[12];
    const float* pr_w  = (const float*)d_in[13];
    const float* pr_b  = (const float*)d_in[14];
    const float* lnfw  = (const float*)d_in[15];
    const float* lnfb  = (const float*)d_in[16];
    float* outp = (float*)d_out;

    char* ws = (char*)d_ws;
    float* h   = (float*)ws;                        // 25,165,824 B
    u16* ybuf  = (u16*)(ws + 25165824);             // 12,582,912 B
    u16* big   = (u16*)(ws + 37748736);             // 50,331,648 B (qT+kT / fc act)
    u16* qT    = big;                               // 6,291,456 elems
    u16* kT    = big + 6291456;                     // 6,291,456 elems
    u16* vT    = (u16*)(ws + 88080384);             // 12,582,912 B
    u16* wb    = (u16*)(ws + 100663296);            // 56,623,104 B
    u16* w_in  = wb;                                // 4*2304*768
    u16* w_out = w_in + 7077888;                    // 4*768*768
    u16* w_fc  = w_out + 2359296;                   // 4*3072*768
    u16* w_pr  = w_fc + 9437184;                    // 4*768*3072

    cvt_k<<<1024, 256, 0, stream>>>(in_w,  w_in,  7077888 / 4);
    cvt_k<<<1024, 256, 0, stream>>>(out_w, w_out, 2359296 / 4);
    cvt_k<<<1024, 256, 0, stream>>>(fc_w,  w_fc,  9437184 / 4);
    cvt_k<<<1024, 256, 0, stream>>>(pr_w,  w_pr,  9437184 / 4);
    embed_k<<<6144, 256, 0, stream>>>(x, sd, wpe, h);

    for (int l = 0; l < LL; l++) {
        ln_k<true><<<2048, 256, 0, stream>>>(h, ln1w + l * EE, ln1b + l * EE, ybuf);
        gemm_bt<0><<<18 * 64, 256, 0, stream>>>(
            ybuf, w_in + (size_t)l * 2304 * 768, in_b + l * 2304, nullptr, qT, vT, kT,
            8192, 2304, 768);
        attn_k<<<1536, 256, 0, stream>>>(qT, kT, vT, ybuf);
        gemm_bt<1><<<6 * 64, 256, 0, stream>>>(
            ybuf, w_out + (size_t)l * 768 * 768, out_b + l * 768, h, nullptr, nullptr, nullptr,
            8192, 768, 768);
        ln_k<true><<<2048, 256, 0, stream>>>(h, ln2w + l * EE, ln2b + l * EE, ybuf);
        gemm_bt<2><<<24 * 64, 256, 0, stream>>>(
            ybuf, w_fc + (size_t)l * 3072 * 768, fc_b + l * 3072, nullptr, big, nullptr, nullptr,
            8192, 3072, 768);
        gemm_bt<1><<<6 * 64, 256, 0, stream>>>(
            big, w_pr + (size_t)l * 768 * 3072, pr_b + l * 768, h, nullptr, nullptr, nullptr,
            8192, 768, 3072);
    }
    ln_k<false><<<2048, 256, 0, stream>>>(h, lnfw, lnfb, outp);
}

// Round 4
// 1343.224 us; speedup vs baseline: 1.5354x; 1.0404x over previous
//
#include <hip/hip_runtime.h>
#include <hip/hip_bf16.h>

// ---------- types ----------
typedef __attribute__((ext_vector_type(8))) __bf16 bf16x8;
typedef __attribute__((ext_vector_type(4))) float f32x4;

typedef unsigned short u16;

__device__ __forceinline__ u16 f2bf(float f) {
    unsigned int u = __float_as_uint(f);
    u += 0x7FFFu + ((u >> 16) & 1u);   // round-to-nearest-even
    return (u16)(u >> 16);
}

__device__ __forceinline__ void g2l16(const void* g, void* l) {
    __builtin_amdgcn_global_load_lds(
        (const __attribute__((address_space(1))) void*)g,
        (__attribute__((address_space(3))) void*)l, 16, 0, 0);
}

// ---------- constants ----------
#define BB 8
#define SS 1024
#define EE 768
#define HH 12
#define HD 64
#define LL 4

// ---------- fp32 -> bf16 convert ----------
__global__ __launch_bounds__(256) void cvt_k(const float* __restrict__ in,
                                             u16* __restrict__ out, int n4) {
    for (int i = blockIdx.x * 256 + threadIdx.x; i < n4; i += gridDim.x * 256) {
        float4 v = ((const float4*)in)[i];
        ushort4 u;
        u.x = f2bf(v.x); u.y = f2bf(v.y); u.z = f2bf(v.z); u.w = f2bf(v.w);
        ((ushort4*)out)[i] = u;
    }
}

// ---------- embed: h = x + wpe[study_date] ----------
__global__ __launch_bounds__(256) void embed_k(const float* __restrict__ x,
                                               const int* __restrict__ sd,
                                               const float* __restrict__ wpe,
                                               float* __restrict__ h) {
    int idx = blockIdx.x * 256 + threadIdx.x;          // over 8192*192 float4s
    int e4 = idx % 192;
    int bs = idx / 192;
    int b = bs >> 10;
    int t = (bs >> 5) & 31;
    int date = sd[b * 32 + t];
    date = date < 0 ? 0 : (date > 49 ? 49 : date);
    float4 xv = ((const float4*)x)[idx];
    float4 pv = ((const float4*)wpe)[date * 192 + e4];
    float4 r; r.x = xv.x + pv.x; r.y = xv.y + pv.y; r.z = xv.z + pv.z; r.w = xv.w + pv.w;
    ((float4*)h)[idx] = r;
}

// ---------- layernorm: wave per token ----------
template <bool BF16OUT>
__global__ __launch_bounds__(256) void ln_k(const float* __restrict__ in,
                                            const float* __restrict__ w,
                                            const float* __restrict__ b,
                                            void* __restrict__ out) {
    int tid = threadIdx.x, wv = tid >> 6, lane = tid & 63;
    int token = blockIdx.x * 4 + wv;
    const float4* ip = (const float4*)(in + (size_t)token * EE);
    float4 v[3];
#pragma unroll
    for (int p = 0; p < 3; p++) v[p] = ip[p * 64 + lane];
    float s = 0.f;
#pragma unroll
    for (int p = 0; p < 3; p++) s += v[p].x + v[p].y + v[p].z + v[p].w;
#pragma unroll
    for (int m = 1; m < 64; m <<= 1) s += __shfl_xor(s, m);
    float mean = s * (1.f / 768.f);
    float vs = 0.f;
#pragma unroll
    for (int p = 0; p < 3; p++) {
        float dx = v[p].x - mean, dy = v[p].y - mean, dz = v[p].z - mean, dw = v[p].w - mean;
        vs += dx * dx + dy * dy + dz * dz + dw * dw;
    }
#pragma unroll
    for (int m = 1; m < 64; m <<= 1) vs += __shfl_xor(vs, m);
    float rstd = rsqrtf(vs * (1.f / 768.f) + 1e-5f);
    const float4* wp = (const float4*)w;
    const float4* bp = (const float4*)b;
#pragma unroll
    for (int p = 0; p < 3; p++) {
        float4 wv4 = wp[p * 64 + lane], bv4 = bp[p * 64 + lane];
        float rx = (v[p].x - mean) * rstd * wv4.x + bv4.x;
        float ry = (v[p].y - mean) * rstd * wv4.y + bv4.y;
        float rz = (v[p].z - mean) * rstd * wv4.z + bv4.z;
        float rw = (v[p].w - mean) * rstd * wv4.w + bv4.w;
        if (BF16OUT) {
            ushort4 u; u.x = f2bf(rx); u.y = f2bf(ry); u.z = f2bf(rz); u.w = f2bf(rw);
            ((ushort4*)((u16*)out + (size_t)token * EE))[p * 64 + lane] = u;
        } else {
            float4 r; r.x = rx; r.y = ry; r.z = rz; r.w = rw;
            ((float4*)((float*)out + (size_t)token * EE))[p * 64 + lane] = r;
        }
    }
}

// ---------- GEMM: C[M,N] = A[M,K](bf16) * Bw[N,K]^T(bf16) + bias ----------
// BM x 128 tile (BM=128 or 64). 1-D grid, XCD-aware remap: id%8 = XCD owns a
// contiguous band of M-tiles, walking N fastest (A band L2-resident, B streamed).
// LDS double-buffered, ONE barrier per K-iter.
// BM=64 for N=768 GEMMs: grid 768 blocks -> 3 blocks/CU (vs 1.5 at BM=128).
// MODE 0: QKV epilogue  (q -> qT [B,H,S,HD]; k -> kT [B,H,S,HD]; v -> vT [B,H,HD,S])
// MODE 1: residual      (hres[M,N] += C + bias)
// MODE 2: NewGELU       (outb[M,N] = bf16(gelu(C + bias)))
template <int MODE, int BM>
__global__ __launch_bounds__(256) void gemm_bt(const u16* __restrict__ A,
                                               const u16* __restrict__ Bw,
                                               const float* __restrict__ bias,
                                               float* __restrict__ hres,
                                               u16* __restrict__ outb,
                                               u16* __restrict__ vT,
                                               u16* __restrict__ kT,
                                               int M, int N, int K) {
    constexpr int TM = BM / 32;          // acc m-tiles per wave (4 or 2)
    constexpr int ABUF = BM * 32;        // u16 per A buffer
    __shared__ u16 As[2][ABUF];          // BM rows x 32 cols, 16B-chunk swizzled
    __shared__ u16 Bs[2][4096];          // 128 rows x 32 cols
    const int tid = threadIdx.x;
    const int lane = tid & 63, w = tid >> 6;
    const int quad = lane >> 4, l16 = lane & 15;

    // XCD-aware block remap
    const int nx = N >> 7;
    const int ny = M / BM;
    const int id = blockIdx.x;
    const int xcd = id & 7, s = id >> 3;
    const int yt = xcd * (ny >> 3) + s / nx;
    const int xt = s % nx;
    const int m0 = yt * BM, n0 = xt * 128;
    const int wm = (w >> 1) * (BM / 2), wn = (w & 1) * 64;

    f32x4 acc[TM][4];
#pragma unroll
    for (int i = 0; i < TM; i++)
#pragma unroll
        for (int j = 0; j < 4; j++) acc[i][j] = (f32x4){0.f, 0.f, 0.f, 0.f};

    // staging: chunk c holds row (c>>2), k-chunk ((c&3)^((c>>3)&3))
    // B: 512 chunks, 2 per thread
    const int cB0 = w * 128 + lane, cB1 = cB0 + 64;
    const int rB0 = cB0 >> 2, gB0 = (((cB0 & 3) ^ ((cB0 >> 3) & 3)) * 8);
    const int rB1 = cB1 >> 2, gB1 = (((cB1 & 3) ^ ((cB1 >> 3) & 3)) * 8);
    const u16* Bp0 = Bw + (size_t)(n0 + rB0) * K + gB0;
    const u16* Bp1 = Bw + (size_t)(n0 + rB1) * K + gB1;
    char* lB0 = (char*)Bs + w * 2048;
    char* lB1 = (char*)Bs + w * 2048 + 1024;
    // A: BM*4 chunks (2 per thread at BM=128, 1 at BM=64)
    const int cA0 = (BM == 128) ? cB0 : (w * 64 + lane);
    const int rA0 = cA0 >> 2, gA0 = (((cA0 & 3) ^ ((cA0 >> 3) & 3)) * 8);
    const u16* Ap0 = A + (size_t)(m0 + rA0) * K + gA0;
    char* lA0 = (char*)As + ((BM == 128) ? w * 2048 : w * 1024);
    const int cA1 = cB1;
    const int rA1 = cA1 >> 2, gA1 = (((cA1 & 3) ^ ((cA1 >> 3) & 3)) * 8);
    const u16* Ap1 = A + (size_t)(m0 + rA1) * K + gA1;
    char* lA1 = (char*)As + w * 2048 + 1024;

    const int swz = (quad ^ ((l16 >> 1) & 3)) * 8;

    const int nk = K >> 5;
    // prologue: stage tile 0 into buffer 0
    g2l16(Ap0, lA0);
    if (BM == 128) g2l16(Ap1, lA1);
    g2l16(Bp0, lB0); g2l16(Bp1, lB1);

    for (int ki = 0; ki < nk; ki++) {
        __syncthreads();  // tile ki ready; buffer ki^1 free (reads done pre-barrier)
        if (ki + 1 < nk) {
            const int kb = (ki + 1) << 5;
            const int boA = ((ki + 1) & 1) * (ABUF * 2);
            const int boB = ((ki + 1) & 1) * 8192;
            g2l16(Ap0 + kb, lA0 + boA);
            if (BM == 128) g2l16(Ap1 + kb, lA1 + boA);
            g2l16(Bp0 + kb, lB0 + boB);
            g2l16(Bp1 + kb, lB1 + boB);
        }
        const u16* Ab = (const u16*)As + (ki & 1) * ABUF;
        const u16* Bb = (const u16*)Bs + (ki & 1) * 4096;
        bf16x8 af[TM], bfr[4];
#pragma unroll
        for (int t = 0; t < TM; t++) {
            int rowA = wm + t * 16 + l16;
            af[t] = *(const bf16x8*)(Ab + rowA * 32 + swz);
        }
#pragma unroll
        for (int t = 0; t < 4; t++) {
            int rowB = wn + t * 16 + l16;
            bfr[t] = *(const bf16x8*)(Bb + rowB * 32 + swz);
        }
#pragma unroll
        for (int tm = 0; tm < TM; tm++)
#pragma unroll
            for (int tn = 0; tn < 4; tn++)
                acc[tm][tn] = __builtin_amdgcn_mfma_f32_16x16x32_bf16(
                    af[tm], bfr[tn], acc[tm][tn], 0, 0, 0);
    }

    // epilogue: C row = m0+wm+tm*16+quad*4+r ; col = n0+wn+tn*16+l16
#pragma unroll
    for (int tm = 0; tm < TM; tm++) {
        int rowm = m0 + wm + tm * 16 + quad * 4;
#pragma unroll
        for (int tn = 0; tn < 4; tn++) {
            int coln = n0 + wn + tn * 16 + l16;
            float bv = bias[coln];
            f32x4 v = acc[tm][tn];
            if (MODE == 0) {
                int b = rowm >> 10, s2 = rowm & 1023;
                if (coln < EE) {
                    int hh = coln >> 6, d = coln & 63;
                    u16* qp = outb + ((size_t)(b * HH + hh) * SS + s2) * HD + d;
#pragma unroll
                    for (int r = 0; r < 4; r++) qp[r * HD] = f2bf(v[r] + bv);
                } else if (coln < 2 * EE) {
                    int hh = (coln - EE) >> 6, d = (coln - EE) & 63;
                    u16* kp = kT + ((size_t)(b * HH + hh) * SS + s2) * HD + d;
#pragma unroll
                    for (int r = 0; r < 4; r++) kp[r * HD] = f2bf(v[r] + bv);
                } else {
                    int hh = (coln - 2 * EE) >> 6, d = (coln - 2 * EE) & 63;
                    ushort4 pk;
                    pk.x = f2bf(v[0] + bv); pk.y = f2bf(v[1] + bv);
                    pk.z = f2bf(v[2] + bv); pk.w = f2bf(v[3] + bv);
                    *(ushort4*)(vT + (((size_t)((b * HH + hh) * HD + d)) << 10) + s2) = pk;
                }
            } else if (MODE == 1) {
#pragma unroll
                for (int r = 0; r < 4; r++) {
                    size_t idx = (size_t)(rowm + r) * N + coln;
                    hres[idx] += v[r] + bv;
                }
            } else {
#pragma unroll
                for (int r = 0; r < 4; r++) {
                    float x = v[r] + bv;
                    float t = x + 0.044715f * x * x * x;
                    float e = __expf(-1.5957691216057308f * t);  // exp(-2*sqrt(2/pi)*t)
                    float th = (1.f - e) / (1.f + e);
                    outb[(size_t)(rowm + r) * N + coln] = f2bf(0.5f * x * (1.f + th));
                }
            }
        }
    }
}

// ---------- flash attention ----------
// qT,kT: [B,H,S,HD] bf16   vT: [B,H,HD,S] bf16   o: [B*S, 768] bf16
// block = 4 waves = one (b, head, 64 q-rows); K/V tiles staged in LDS, shared by all waves.
// Block-causal: waves 0,1 (rows q0..q0+31) see keys < q0+32; waves 2,3 see < q0+64.
__global__ __launch_bounds__(256) void attn_k(const u16* __restrict__ qT,
                                              const u16* __restrict__ kT,
                                              const u16* __restrict__ vT,
                                              u16* __restrict__ o) {
    __shared__ u16 Ks[2048];        // 32 tokens x 64 d, 16B chunks swizzled
    __shared__ u16 Vs[2048];        // 64 d x 32 tokens, 16B chunks swizzled
    __shared__ u16 P[4][16 * 40];   // per-wave P tile
    int tid = threadIdx.x, w = tid >> 6, lane = tid & 63;
    int quad = lane >> 4, l16 = lane & 15;
    int blk = blockIdx.x;
    int qg = 15 - (blk / 96);       // largest q-groups dispatch first (load balance)
    int bh = blk % 96;              // b*12 + h
    int b = bh / HH, hh = bh % HH;
    int q0 = qg * 64;
    int kend_blk = q0 + 64;
    int kend_w = q0 + ((w >> 1) ? 64 : 32);

    const u16* qbase = qT + ((size_t)bh * SS + q0 + w * 16 + l16) * HD + quad * 8;
    bf16x8 qf0 = *(const bf16x8*)(qbase);
    bf16x8 qf1 = *(const bf16x8*)(qbase + 32);

    f32x4 of[4];
#pragma unroll
    for (int i = 0; i < 4; i++) of[i] = (f32x4){0.f, 0.f, 0.f, 0.f};
    float mrun[4], lrun[4];
#pragma unroll
    for (int r = 0; r < 4; r++) { mrun[r] = -__builtin_inff(); lrun[r] = 0.f; }

    // staging addresses: slot s (=tid) of Ks holds K[token=s>>3][dchunk=(s&7)^(token&7)]
    int tK = tid >> 3, dcK = ((tid & 7) ^ (tK & 7));
    const u16* kg = kT + ((size_t)bh * SS + tK) * HD + dcK * 8;
    char* kl = (char*)Ks + w * 1024;
    // slot s of Vs holds V[d=s>>2][tokchunk=(s&3)^((d>>1)&3)]
    int dV = tid >> 2, tcV = ((tid & 3) ^ ((dV >> 1) & 3));
    const u16* vg = vT + ((size_t)bh * HD + dV) * SS + tcV * 8;
    char* vl = (char*)Vs + w * 1024;
    u16* Pw = P[w];

    for (int kb = 0; kb < kend_blk; kb += 32) {
        g2l16(kg + (size_t)kb * HD, kl);
        g2l16(vg + kb, vl);
        __syncthreads();
        if (kb < kend_w) {
            int t0 = l16, t1 = 16 + l16;
            bf16x8 k00 = *(const bf16x8*)(Ks + (t0 * 8 + (quad ^ (l16 & 7))) * 8);
            bf16x8 k01 = *(const bf16x8*)(Ks + (t0 * 8 + ((4 + quad) ^ (l16 & 7))) * 8);
            bf16x8 k10 = *(const bf16x8*)(Ks + (t1 * 8 + (quad ^ (l16 & 7))) * 8);
            bf16x8 k11 = *(const bf16x8*)(Ks + (t1 * 8 + ((4 + quad) ^ (l16 & 7))) * 8);
            f32x4 s0 = (f32x4){0.f, 0.f, 0.f, 0.f};
            f32x4 s1 = (f32x4){0.f, 0.f, 0.f, 0.f};
            s0 = __builtin_amdgcn_mfma_f32_16x16x32_bf16(qf0, k00, s0, 0, 0, 0);
            s0 = __builtin_amdgcn_mfma_f32_16x16x32_bf16(qf1, k01, s0, 0, 0, 0);
            s1 = __builtin_amdgcn_mfma_f32_16x16x32_bf16(qf0, k10, s1, 0, 0, 0);
            s1 = __builtin_amdgcn_mfma_f32_16x16x32_bf16(qf1, k11, s1, 0, 0, 0);

            float alpha[4];
#pragma unroll
            for (int r = 0; r < 4; r++) {
                float a0 = s0[r] * 0.125f, a1 = s1[r] * 0.125f;
                float mx = fmaxf(a0, a1);
#pragma unroll
                for (int m = 1; m < 16; m <<= 1) mx = fmaxf(mx, __shfl_xor(mx, m));
                float mnew = fmaxf(mrun[r], mx);
                alpha[r] = __expf(mrun[r] - mnew);
                float p0 = __expf(a0 - mnew);
                float p1 = __expf(a1 - mnew);
                float ps = p0 + p1;
#pragma unroll
                for (int m = 1; m < 16; m <<= 1) ps += __shfl_xor(ps, m);
                lrun[r] = lrun[r] * alpha[r] + ps;
                mrun[r] = mnew;
                Pw[(quad * 4 + r) * 40 + l16] = f2bf(p0);
                Pw[(quad * 4 + r) * 40 + 16 + l16] = f2bf(p1);
            }
#pragma unroll
            for (int n4 = 0; n4 < 4; n4++) {
                of[n4][0] *= alpha[0]; of[n4][1] *= alpha[1];
                of[n4][2] *= alpha[2]; of[n4][3] *= alpha[3];
            }
            // P round-trip is per-wave: only lgkmcnt ordering needed, no barrier
            bf16x8 pf = *(const bf16x8*)(Pw + l16 * 40 + quad * 8);
#pragma unroll
            for (int n4 = 0; n4 < 4; n4++) {
                int d = n4 * 16 + l16;
                bf16x8 vf = *(const bf16x8*)(Vs + (d * 4 + (quad ^ ((d >> 1) & 3))) * 8);
                of[n4] = __builtin_amdgcn_mfma_f32_16x16x32_bf16(pf, vf, of[n4], 0, 0, 0);
            }
        }
        __syncthreads();
    }

    float inv[4];
#pragma unroll
    for (int r = 0; r < 4; r++) inv[r] = 1.f / lrun[r];
#pragma unroll
    for (int n4 = 0; n4 < 4; n4++)
#pragma unroll
        for (int r = 0; r < 4; r++)
            o[(size_t)(b * SS + q0 + w * 16 + quad * 4 + r) * EE + hh * HD + n4 * 16 + l16] =
                f2bf(of[n4][r] * inv[r]);
}

// ---------- launcher ----------
extern "C" void kernel_launch(void* const* d_in, const int* in_sizes, int n_in,
                              void* d_out, int out_size, void* d_ws, size_t ws_size,
                              hipStream_t stream) {
    const float* x     = (const float*)d_in[0];
    const int*   sd    = (const int*)d_in[1];
    const float* wpe   = (const float*)d_in[2];
    const float* ln1w  = (const float*)d_in[3];
    const float* ln1b  = (const float*)d_in[4];
    const float* in_w  = (const float*)d_in[5];
    const float* in_b  = (const float*)d_in[6];
    const float* out_w = (const float*)d_in[7];
    const float* out_b = (const float*)d_in[8];
    const float* ln2w  = (const float*)d_in[9];
    const float* ln2b  = (const float*)d_in[10];
    const float* fc_w  = (const float*)d_in[11];
    const float* fc_b  = (const float*)d_in[12];
    const float* pr_w  = (const float*)d_in[13];
    const float* pr_b  = (const float*)d_in[14];
    const float* lnfw  = (const float*)d_in[15];
    const float* lnfb  = (const float*)d_in[16];
    float* outp = (float*)d_out;

    char* ws = (char*)d_ws;
    float* h   = (float*)ws;                        // 25,165,824 B
    u16* ybuf  = (u16*)(ws + 25165824);             // 12,582,912 B
    u16* big   = (u16*)(ws + 37748736);             // 50,331,648 B (qT+kT / fc act)
    u16* qT    = big;                               // 6,291,456 elems
    u16* kT    = big + 6291456;                     // 6,291,456 elems
    u16* vT    = (u16*)(ws + 88080384);             // 12,582,912 B
    u16* wb    = (u16*)(ws + 100663296);            // 56,623,104 B
    u16* w_in  = wb;                                // 4*2304*768
    u16* w_out = w_in + 7077888;                    // 4*768*768
    u16* w_fc  = w_out + 2359296;                   // 4*3072*768
    u16* w_pr  = w_fc + 9437184;                    // 4*768*3072

    cvt_k<<<1024, 256, 0, stream>>>(in_w,  w_in,  7077888 / 4);
    cvt_k<<<1024, 256, 0, stream>>>(out_w, w_out, 2359296 / 4);
    cvt_k<<<1024, 256, 0, stream>>>(fc_w,  w_fc,  9437184 / 4);
    cvt_k<<<1024, 256, 0, stream>>>(pr_w,  w_pr,  9437184 / 4);
    embed_k<<<6144, 256, 0, stream>>>(x, sd, wpe, h);

    for (int l = 0; l < LL; l++) {
        ln_k<true><<<2048, 256, 0, stream>>>(h, ln1w + l * EE, ln1b + l * EE, ybuf);
        gemm_bt<0, 128><<<18 * 64, 256, 0, stream>>>(
            ybuf, w_in + (size_t)l * 2304 * 768, in_b + l * 2304, nullptr, qT, vT, kT,
            8192, 2304, 768);
        attn_k<<<1536, 256, 0, stream>>>(qT, kT, vT, ybuf);
        gemm_bt<1, 64><<<6 * 128, 256, 0, stream>>>(
            ybuf, w_out + (size_t)l * 768 * 768, out_b + l * 768, h, nullptr, nullptr, nullptr,
            8192, 768, 768);
        ln_k<true><<<2048, 256, 0, stream>>>(h, ln2w + l * EE, ln2b + l * EE, ybuf);
        gemm_bt<2, 128><<<24 * 64, 256, 0, stream>>>(
            ybuf, w_fc + (size_t)l * 3072 * 768, fc_b + l * 3072, nullptr, big, nullptr, nullptr,
            8192, 3072, 768);
        gemm_bt<1, 64><<<6 * 128, 256, 0, stream>>>(
            big, w_pr + (size_t)l * 768 * 3072, pr_b + l * 768, h, nullptr, nullptr, nullptr,
            8192, 768, 3072);
    }
    ln_k<false><<<2048, 256, 0, stream>>>(h, lnfw, lnfb, outp);
}

// Round 5
// 1331.755 us; speedup vs baseline: 1.5486x; 1.0086x over previous
//
#include <hip/hip_runtime.h>
#include <hip/hip_bf16.h>

// ---------- types ----------
typedef __attribute__((ext_vector_type(8))) __bf16 bf16x8;
typedef __attribute__((ext_vector_type(4))) float f32x4;

typedef unsigned short u16;

__device__ __forceinline__ u16 f2bf(float f) {
    unsigned int u = __float_as_uint(f);
    u += 0x7FFFu + ((u >> 16) & 1u);   // round-to-nearest-even
    return (u16)(u >> 16);
}

__device__ __forceinline__ void g2l16(const void* g, void* l) {
    __builtin_amdgcn_global_load_lds(
        (const __attribute__((address_space(1))) void*)g,
        (__attribute__((address_space(3))) void*)l, 16, 0, 0);
}

// ---------- constants ----------
#define BB 8
#define SS 1024
#define EE 768
#define HH 12
#define HD 64
#define LL 4

// ---------- fp32 -> bf16 convert ----------
__global__ __launch_bounds__(256) void cvt_k(const float* __restrict__ in,
                                             u16* __restrict__ out, int n4) {
    for (int i = blockIdx.x * 256 + threadIdx.x; i < n4; i += gridDim.x * 256) {
        float4 v = ((const float4*)in)[i];
        ushort4 u;
        u.x = f2bf(v.x); u.y = f2bf(v.y); u.z = f2bf(v.z); u.w = f2bf(v.w);
        ((ushort4*)out)[i] = u;
    }
}

// ---------- embed: h = x + wpe[study_date] ----------
__global__ __launch_bounds__(256) void embed_k(const float* __restrict__ x,
                                               const int* __restrict__ sd,
                                               const float* __restrict__ wpe,
                                               float* __restrict__ h) {
    int idx = blockIdx.x * 256 + threadIdx.x;          // over 8192*192 float4s
    int e4 = idx % 192;
    int bs = idx / 192;
    int b = bs >> 10;
    int t = (bs >> 5) & 31;
    int date = sd[b * 32 + t];
    date = date < 0 ? 0 : (date > 49 ? 49 : date);
    float4 xv = ((const float4*)x)[idx];
    float4 pv = ((const float4*)wpe)[date * 192 + e4];
    float4 r; r.x = xv.x + pv.x; r.y = xv.y + pv.y; r.z = xv.z + pv.z; r.w = xv.w + pv.w;
    ((float4*)h)[idx] = r;
}

// ---------- layernorm: wave per token ----------
template <bool BF16OUT>
__global__ __launch_bounds__(256) void ln_k(const float* __restrict__ in,
                                            const float* __restrict__ w,
                                            const float* __restrict__ b,
                                            void* __restrict__ out) {
    int tid = threadIdx.x, wv = tid >> 6, lane = tid & 63;
    int token = blockIdx.x * 4 + wv;
    const float4* ip = (const float4*)(in + (size_t)token * EE);
    float4 v[3];
#pragma unroll
    for (int p = 0; p < 3; p++) v[p] = ip[p * 64 + lane];
    float s = 0.f;
#pragma unroll
    for (int p = 0; p < 3; p++) s += v[p].x + v[p].y + v[p].z + v[p].w;
#pragma unroll
    for (int m = 1; m < 64; m <<= 1) s += __shfl_xor(s, m);
    float mean = s * (1.f / 768.f);
    float vs = 0.f;
#pragma unroll
    for (int p = 0; p < 3; p++) {
        float dx = v[p].x - mean, dy = v[p].y - mean, dz = v[p].z - mean, dw = v[p].w - mean;
        vs += dx * dx + dy * dy + dz * dz + dw * dw;
    }
#pragma unroll
    for (int m = 1; m < 64; m <<= 1) vs += __shfl_xor(vs, m);
    float rstd = rsqrtf(vs * (1.f / 768.f) + 1e-5f);
    const float4* wp = (const float4*)w;
    const float4* bp = (const float4*)b;
#pragma unroll
    for (int p = 0; p < 3; p++) {
        float4 wv4 = wp[p * 64 + lane], bv4 = bp[p * 64 + lane];
        float rx = (v[p].x - mean) * rstd * wv4.x + bv4.x;
        float ry = (v[p].y - mean) * rstd * wv4.y + bv4.y;
        float rz = (v[p].z - mean) * rstd * wv4.z + bv4.z;
        float rw = (v[p].w - mean) * rstd * wv4.w + bv4.w;
        if (BF16OUT) {
            ushort4 u; u.x = f2bf(rx); u.y = f2bf(ry); u.z = f2bf(rz); u.w = f2bf(rw);
            ((ushort4*)((u16*)out + (size_t)token * EE))[p * 64 + lane] = u;
        } else {
            float4 r; r.x = rx; r.y = ry; r.z = rz; r.w = rw;
            ((float4*)((float*)out + (size_t)token * EE))[p * 64 + lane] = r;
        }
    }
}

// ---------- GEMM: C[M,N] = A[M,K](bf16) * Bw[N,K]^T(bf16) + bias ----------
// 1-D grid, XCD-aware remap: id%8 = XCD owns a contiguous band of M-tiles,
// walking N fastest (A band L2-resident, B streamed).
// BM=128: double-buffered LDS, __syncthreads per K-iter (plenty of TLP at
//         5 blocks/CU for the big-N GEMMs).
// BM=64 (N=768 GEMMs, grid-capped at 3 blocks/CU): QUAD-buffered LDS,
//         prefetch distance 2, raw s_waitcnt vmcnt(6)+s_barrier so prefetch
//         stays in flight across the barrier (no vmcnt(0) drain) — covers
//         ~900-cyc HBM miss latency that __syncthreads structurally cannot.
// MODE 0: QKV epilogue  (q -> qT [B,H,S,HD]; k -> kT [B,H,S,HD]; v -> vT [B,H,HD,S])
// MODE 1: residual      (hres[M,N] += C + bias)
// MODE 2: NewGELU       (outb[M,N] = bf16(gelu(C + bias)))
template <int MODE, int BM>
__global__ __launch_bounds__(256) void gemm_bt(const u16* __restrict__ A,
                                               const u16* __restrict__ Bw,
                                               const float* __restrict__ bias,
                                               float* __restrict__ hres,
                                               u16* __restrict__ outb,
                                               u16* __restrict__ vT,
                                               u16* __restrict__ kT,
                                               int M, int N, int K) {
    constexpr int TM = BM / 32;          // acc m-tiles per wave (4 or 2)
    const int tid = threadIdx.x;
    const int lane = tid & 63, w = tid >> 6;
    const int quad = lane >> 4, l16 = lane & 15;

    // XCD-aware block remap
    const int nx = N >> 7;
    const int ny = M / BM;
    const int id = blockIdx.x;
    const int xcd = id & 7, s = id >> 3;
    const int yt = xcd * (ny >> 3) + s / nx;
    const int xt = s % nx;
    const int m0 = yt * BM, n0 = xt * 128;
    const int wm = (w >> 1) * (BM / 2), wn = (w & 1) * 64;

    f32x4 acc[TM][4];
#pragma unroll
    for (int i = 0; i < TM; i++)
#pragma unroll
        for (int j = 0; j < 4; j++) acc[i][j] = (f32x4){0.f, 0.f, 0.f, 0.f};

    const int swz = (quad ^ ((l16 >> 1) & 3)) * 8;
    const int nk = K >> 5;

    if constexpr (BM == 128) {
        __shared__ u16 As[2][4096];          // 128 rows x 32 cols, swizzled
        __shared__ u16 Bs[2][4096];
        const int c0 = w * 128 + lane, c1 = c0 + 64;
        const int r0 = c0 >> 2, g0 = (((c0 & 3) ^ ((c0 >> 3) & 3)) * 8);
        const int r1 = c1 >> 2, g1 = (((c1 & 3) ^ ((c1 >> 3) & 3)) * 8);
        const u16* Ap0 = A + (size_t)(m0 + r0) * K + g0;
        const u16* Ap1 = A + (size_t)(m0 + r1) * K + g1;
        const u16* Bp0 = Bw + (size_t)(n0 + r0) * K + g0;
        const u16* Bp1 = Bw + (size_t)(n0 + r1) * K + g1;
        char* lA0 = (char*)As + w * 2048;
        char* lA1 = (char*)As + w * 2048 + 1024;
        char* lB0 = (char*)Bs + w * 2048;
        char* lB1 = (char*)Bs + w * 2048 + 1024;

        g2l16(Ap0, lA0); g2l16(Ap1, lA1); g2l16(Bp0, lB0); g2l16(Bp1, lB1);

        for (int ki = 0; ki < nk; ki++) {
            __syncthreads();
            if (ki + 1 < nk) {
                const int kb = (ki + 1) << 5;
                const int bo = ((ki + 1) & 1) * 8192;
                g2l16(Ap0 + kb, lA0 + bo);
                g2l16(Ap1 + kb, lA1 + bo);
                g2l16(Bp0 + kb, lB0 + bo);
                g2l16(Bp1 + kb, lB1 + bo);
            }
            const u16* Ab = (const u16*)As + (ki & 1) * 4096;
            const u16* Bb = (const u16*)Bs + (ki & 1) * 4096;
            bf16x8 af[TM], bfr[4];
#pragma unroll
            for (int t = 0; t < TM; t++)
                af[t] = *(const bf16x8*)(Ab + (wm + t * 16 + l16) * 32 + swz);
#pragma unroll
            for (int t = 0; t < 4; t++)
                bfr[t] = *(const bf16x8*)(Bb + (wn + t * 16 + l16) * 32 + swz);
#pragma unroll
            for (int tm = 0; tm < TM; tm++)
#pragma unroll
                for (int tn = 0; tn < 4; tn++)
                    acc[tm][tn] = __builtin_amdgcn_mfma_f32_16x16x32_bf16(
                        af[tm], bfr[tn], acc[tm][tn], 0, 0, 0);
        }
    } else {
        // BM == 64: quad-buffer, prefetch distance 2.
        // buffer t: A = SM + t*6144 (2048 u16), B = SM + t*6144 + 2048 (4096 u16)
        __shared__ u16 SM[4 * 6144];
        const int cA = tid;                          // 256 A-chunks (64 rows x 4)
        const int rA = cA >> 2, gA = (((cA & 3) ^ ((cA >> 3) & 3)) * 8);
        const u16* Ap = A + (size_t)(m0 + rA) * K + gA;
        const int cB0 = w * 128 + lane, cB1 = cB0 + 64;
        const int rB0 = cB0 >> 2, gB0 = (((cB0 & 3) ^ ((cB0 >> 3) & 3)) * 8);
        const int rB1 = cB1 >> 2, gB1 = (((cB1 & 3) ^ ((cB1 >> 3) & 3)) * 8);
        const u16* Bp0 = Bw + (size_t)(n0 + rB0) * K + gB0;
        const u16* Bp1 = Bw + (size_t)(n0 + rB1) * K + gB1;
        char* lA = (char*)SM + w * 1024;             // + buf*12288
        char* lB0 = (char*)SM + 4096 + w * 2048;     // + buf*12288
        char* lB1 = (char*)SM + 4096 + w * 2048 + 1024;

        // prologue: stage tiles 0 and 1 (3 loads/thread each)
        g2l16(Ap, lA);
        g2l16(Bp0, lB0);
        g2l16(Bp1, lB1);
        g2l16(Ap + 32, lA + 12288);
        g2l16(Bp0 + 32, lB0 + 12288);
        g2l16(Bp1 + 32, lB1 + 12288);

        for (int ki = 0; ki < nk; ki++) {
            if (ki + 2 < nk) {
                const int kb = (ki + 2) << 5;
                const int bo = ((ki + 2) & 3) * 12288;
                g2l16(Ap + kb, lA + bo);
                g2l16(Bp0 + kb, lB0 + bo);
                g2l16(Bp1 + kb, lB1 + bo);
            }
            // tile ki landed when ≤ 2 tiles (6 loads/thread) remain outstanding
            if (ki < nk - 2)       __builtin_amdgcn_s_waitcnt(0x0F76);  // vmcnt(6)
            else if (ki == nk - 2) __builtin_amdgcn_s_waitcnt(0x0F73);  // vmcnt(3)
            else                   __builtin_amdgcn_s_waitcnt(0x0F70);  // vmcnt(0)
            __builtin_amdgcn_s_barrier();

            const u16* Ab = (const u16*)SM + (ki & 3) * 6144;
            const u16* Bb = Ab + 2048;
            bf16x8 af[TM], bfr[4];
#pragma unroll
            for (int t = 0; t < TM; t++)
                af[t] = *(const bf16x8*)(Ab + (wm + t * 16 + l16) * 32 + swz);
#pragma unroll
            for (int t = 0; t < 4; t++)
                bfr[t] = *(const bf16x8*)(Bb + (wn + t * 16 + l16) * 32 + swz);
#pragma unroll
            for (int tm = 0; tm < TM; tm++)
#pragma unroll
                for (int tn = 0; tn < 4; tn++)
                    acc[tm][tn] = __builtin_amdgcn_mfma_f32_16x16x32_bf16(
                        af[tm], bfr[tn], acc[tm][tn], 0, 0, 0);
        }
    }

    // epilogue: C row = m0+wm+tm*16+quad*4+r ; col = n0+wn+tn*16+l16
#pragma unroll
    for (int tm = 0; tm < TM; tm++) {
        int rowm = m0 + wm + tm * 16 + quad * 4;
#pragma unroll
        for (int tn = 0; tn < 4; tn++) {
            int coln = n0 + wn + tn * 16 + l16;
            float bv = bias[coln];
            f32x4 v = acc[tm][tn];
            if (MODE == 0) {
                int b = rowm >> 10, s2 = rowm & 1023;
                if (coln < EE) {
                    int hh = coln >> 6, d = coln & 63;
                    u16* qp = outb + ((size_t)(b * HH + hh) * SS + s2) * HD + d;
#pragma unroll
                    for (int r = 0; r < 4; r++) qp[r * HD] = f2bf(v[r] + bv);
                } else if (coln < 2 * EE) {
                    int hh = (coln - EE) >> 6, d = (coln - EE) & 63;
                    u16* kp = kT + ((size_t)(b * HH + hh) * SS + s2) * HD + d;
#pragma unroll
                    for (int r = 0; r < 4; r++) kp[r * HD] = f2bf(v[r] + bv);
                } else {
                    int hh = (coln - 2 * EE) >> 6, d = (coln - 2 * EE) & 63;
                    ushort4 pk;
                    pk.x = f2bf(v[0] + bv); pk.y = f2bf(v[1] + bv);
                    pk.z = f2bf(v[2] + bv); pk.w = f2bf(v[3] + bv);
                    *(ushort4*)(vT + (((size_t)((b * HH + hh) * HD + d)) << 10) + s2) = pk;
                }
            } else if (MODE == 1) {
#pragma unroll
                for (int r = 0; r < 4; r++) {
                    size_t idx = (size_t)(rowm + r) * N + coln;
                    hres[idx] += v[r] + bv;
                }
            } else {
#pragma unroll
                for (int r = 0; r < 4; r++) {
                    float x = v[r] + bv;
                    float t = x + 0.044715f * x * x * x;
                    float e = __expf(-1.5957691216057308f * t);  // exp(-2*sqrt(2/pi)*t)
                    float th = (1.f - e) / (1.f + e);
                    outb[(size_t)(rowm + r) * N + coln] = f2bf(0.5f * x * (1.f + th));
                }
            }
        }
    }
}

// ---------- flash attention ----------
// qT,kT: [B,H,S,HD] bf16   vT: [B,H,HD,S] bf16   o: [B*S, 768] bf16
// block = 4 waves = one (b, head, 64 q-rows); K/V tiles staged in LDS, shared by all waves.
// Block-causal: waves 0,1 (rows q0..q0+31) see keys < q0+32; waves 2,3 see < q0+64.
__global__ __launch_bounds__(256) void attn_k(const u16* __restrict__ qT,
                                              const u16* __restrict__ kT,
                                              const u16* __restrict__ vT,
                                              u16* __restrict__ o) {
    __shared__ u16 Ks[2048];        // 32 tokens x 64 d, 16B chunks swizzled
    __shared__ u16 Vs[2048];        // 64 d x 32 tokens, 16B chunks swizzled
    __shared__ u16 P[4][16 * 40];   // per-wave P tile
    int tid = threadIdx.x, w = tid >> 6, lane = tid & 63;
    int quad = lane >> 4, l16 = lane & 15;
    int blk = blockIdx.x;
    int qg = 15 - (blk / 96);       // largest q-groups dispatch first (load balance)
    int bh = blk % 96;              // b*12 + h
    int b = bh / HH, hh = bh % HH;
    int q0 = qg * 64;
    int kend_blk = q0 + 64;
    int kend_w = q0 + ((w >> 1) ? 64 : 32);

    const u16* qbase = qT + ((size_t)bh * SS + q0 + w * 16 + l16) * HD + quad * 8;
    bf16x8 qf0 = *(const bf16x8*)(qbase);
    bf16x8 qf1 = *(const bf16x8*)(qbase + 32);

    f32x4 of[4];
#pragma unroll
    for (int i = 0; i < 4; i++) of[i] = (f32x4){0.f, 0.f, 0.f, 0.f};
    float mrun[4], lrun[4];
#pragma unroll
    for (int r = 0; r < 4; r++) { mrun[r] = -__builtin_inff(); lrun[r] = 0.f; }

    // staging addresses: slot s (=tid) of Ks holds K[token=s>>3][dchunk=(s&7)^(token&7)]
    int tK = tid >> 3, dcK = ((tid & 7) ^ (tK & 7));
    const u16* kg = kT + ((size_t)bh * SS + tK) * HD + dcK * 8;
    char* kl = (char*)Ks + w * 1024;
    // slot s of Vs holds V[d=s>>2][tokchunk=(s&3)^((d>>1)&3)]
    int dV = tid >> 2, tcV = ((tid & 3) ^ ((dV >> 1) & 3));
    const u16* vg = vT + ((size_t)bh * HD + dV) * SS + tcV * 8;
    char* vl = (char*)Vs + w * 1024;
    u16* Pw = P[w];

    for (int kb = 0; kb < kend_blk; kb += 32) {
        g2l16(kg + (size_t)kb * HD, kl);
        g2l16(vg + kb, vl);
        __syncthreads();
        if (kb < kend_w) {
            int t0 = l16, t1 = 16 + l16;
            bf16x8 k00 = *(const bf16x8*)(Ks + (t0 * 8 + (quad ^ (l16 & 7))) * 8);
            bf16x8 k01 = *(const bf16x8*)(Ks + (t0 * 8 + ((4 + quad) ^ (l16 & 7))) * 8);
            bf16x8 k10 = *(const bf16x8*)(Ks + (t1 * 8 + (quad ^ (l16 & 7))) * 8);
            bf16x8 k11 = *(const bf16x8*)(Ks + (t1 * 8 + ((4 + quad) ^ (l16 & 7))) * 8);
            f32x4 s0 = (f32x4){0.f, 0.f, 0.f, 0.f};
            f32x4 s1 = (f32x4){0.f, 0.f, 0.f, 0.f};
            s0 = __builtin_amdgcn_mfma_f32_16x16x32_bf16(qf0, k00, s0, 0, 0, 0);
            s0 = __builtin_amdgcn_mfma_f32_16x16x32_bf16(qf1, k01, s0, 0, 0, 0);
            s1 = __builtin_amdgcn_mfma_f32_16x16x32_bf16(qf0, k10, s1, 0, 0, 0);
            s1 = __builtin_amdgcn_mfma_f32_16x16x32_bf16(qf1, k11, s1, 0, 0, 0);

            float alpha[4];
#pragma unroll
            for (int r = 0; r < 4; r++) {
                float a0 = s0[r] * 0.125f, a1 = s1[r] * 0.125f;
                float mx = fmaxf(a0, a1);
#pragma unroll
                for (int m = 1; m < 16; m <<= 1) mx = fmaxf(mx, __shfl_xor(mx, m));
                float mnew = fmaxf(mrun[r], mx);
                alpha[r] = __expf(mrun[r] - mnew);
                float p0 = __expf(a0 - mnew);
                float p1 = __expf(a1 - mnew);
                float ps = p0 + p1;
#pragma unroll
                for (int m = 1; m < 16; m <<= 1) ps += __shfl_xor(ps, m);
                lrun[r] = lrun[r] * alpha[r] + ps;
                mrun[r] = mnew;
                Pw[(quad * 4 + r) * 40 + l16] = f2bf(p0);
                Pw[(quad * 4 + r) * 40 + 16 + l16] = f2bf(p1);
            }
#pragma unroll
            for (int n4 = 0; n4 < 4; n4++) {
                of[n4][0] *= alpha[0]; of[n4][1] *= alpha[1];
                of[n4][2] *= alpha[2]; of[n4][3] *= alpha[3];
            }
            // P round-trip is per-wave: only lgkmcnt ordering needed, no barrier
            bf16x8 pf = *(const bf16x8*)(Pw + l16 * 40 + quad * 8);
#pragma unroll
            for (int n4 = 0; n4 < 4; n4++) {
                int d = n4 * 16 + l16;
                bf16x8 vf = *(const bf16x8*)(Vs + (d * 4 + (quad ^ ((d >> 1) & 3))) * 8);
                of[n4] = __builtin_amdgcn_mfma_f32_16x16x32_bf16(pf, vf, of[n4], 0, 0, 0);
            }
        }
        __syncthreads();
    }

    float inv[4];
#pragma unroll
    for (int r = 0; r < 4; r++) inv[r] = 1.f / lrun[r];
#pragma unroll
    for (int n4 = 0; n4 < 4; n4++)
#pragma unroll
        for (int r = 0; r < 4; r++)
            o[(size_t)(b * SS + q0 + w * 16 + quad * 4 + r) * EE + hh * HD + n4 * 16 + l16] =
                f2bf(of[n4][r] * inv[r]);
}

// ---------- launcher ----------
extern "C" void kernel_launch(void* const* d_in, const int* in_sizes, int n_in,
                              void* d_out, int out_size, void* d_ws, size_t ws_size,
                              hipStream_t stream) {
    const float* x     = (const float*)d_in[0];
    const int*   sd    = (const int*)d_in[1];
    const float* wpe   = (const float*)d_in[2];
    const float* ln1w  = (const float*)d_in[3];
    const float* ln1b  = (const float*)d_in[4];
    const float* in_w  = (const float*)d_in[5];
    const float* in_b  = (const float*)d_in[6];
    const float* out_w = (const float*)d_in[7];
    const float* out_b = (const float*)d_in[8];
    const float* ln2w  = (const float*)d_in[9];
    const float* ln2b  = (const float*)d_in[10];
    const float* fc_w  = (const float*)d_in[11];
    const float* fc_b  = (const float*)d_in[12];
    const float* pr_w  = (const float*)d_in[13];
    const float* pr_b  = (const float*)d_in[14];
    const float* lnfw  = (const float*)d_in[15];
    const float* lnfb  = (const float*)d_in[16];
    float* outp = (float*)d_out;

    char* ws = (char*)d_ws;
    float* h   = (float*)ws;                        // 25,165,824 B
    u16* ybuf  = (u16*)(ws + 25165824);             // 12,582,912 B
    u16* big   = (u16*)(ws + 37748736);             // 50,331,648 B (qT+kT / fc act)
    u16* qT    = big;                               // 6,291,456 elems
    u16* kT    = big + 6291456;                     // 6,291,456 elems
    u16* vT    = (u16*)(ws + 88080384);             // 12,582,912 B
    u16* wb    = (u16*)(ws + 100663296);            // 56,623,104 B
    u16* w_in  = wb;                                // 4*2304*768
    u16* w_out = w_in + 7077888;                    // 4*768*768
    u16* w_fc  = w_out + 2359296;                   // 4*3072*768
    u16* w_pr  = w_fc + 9437184;                    // 4*768*3072

    cvt_k<<<1024, 256, 0, stream>>>(in_w,  w_in,  7077888 / 4);
    cvt_k<<<1024, 256, 0, stream>>>(out_w, w_out, 2359296 / 4);
    cvt_k<<<1024, 256, 0, stream>>>(fc_w,  w_fc,  9437184 / 4);
    cvt_k<<<1024, 256, 0, stream>>>(pr_w,  w_pr,  9437184 / 4);
    embed_k<<<6144, 256, 0, stream>>>(x, sd, wpe, h);

    for (int l = 0; l < LL; l++) {
        ln_k<true><<<2048, 256, 0, stream>>>(h, ln1w + l * EE, ln1b + l * EE, ybuf);
        gemm_bt<0, 128><<<18 * 64, 256, 0, stream>>>(
            ybuf, w_in + (size_t)l * 2304 * 768, in_b + l * 2304, nullptr, qT, vT, kT,
            8192, 2304, 768);
        attn_k<<<1536, 256, 0, stream>>>(qT, kT, vT, ybuf);
        gemm_bt<1, 64><<<6 * 128, 256, 0, stream>>>(
            ybuf, w_out + (size_t)l * 768 * 768, out_b + l * 768, h, nullptr, nullptr, nullptr,
            8192, 768, 768);
        ln_k<true><<<2048, 256, 0, stream>>>(h, ln2w + l * EE, ln2b + l * EE, ybuf);
        gemm_bt<2, 128><<<24 * 64, 256, 0, stream>>>(
            ybuf, w_fc + (size_t)l * 3072 * 768, fc_b + l * 3072, nullptr, big, nullptr, nullptr,
            8192, 3072, 768);
        gemm_bt<1, 64><<<6 * 128, 256, 0, stream>>>(
            big, w_pr + (size_t)l * 768 * 3072, pr_b + l * 768, h, nullptr, nullptr, nullptr,
            8192, 768, 3072);
    }
    ln_k<false><<<2048, 256, 0, stream>>>(h, lnfw, lnfb, outp);
}

// Round 6
// 1301.961 us; speedup vs baseline: 1.5840x; 1.0229x over previous
//
#include <hip/hip_runtime.h>
#include <hip/hip_bf16.h>

// ---------- types ----------
typedef __attribute__((ext_vector_type(8))) __bf16 bf16x8;
typedef __attribute__((ext_vector_type(4))) float f32x4;

typedef unsigned short u16;

__device__ __forceinline__ u16 f2bf(float f) {
    unsigned int u = __float_as_uint(f);
    u += 0x7FFFu + ((u >> 16) & 1u);   // round-to-nearest-even
    return (u16)(u >> 16);
}

__device__ __forceinline__ void g2l16(const void* g, void* l) {
    __builtin_amdgcn_global_load_lds(
        (const __attribute__((address_space(1))) void*)g,
        (__attribute__((address_space(3))) void*)l, 16, 0, 0);
}

// ---------- constants ----------
#define BB 8
#define SS 1024
#define EE 768
#define HH 12
#define HD 64
#define LL 4

// ---------- fp32 -> bf16 convert ----------
__global__ __launch_bounds__(256) void cvt_k(const float* __restrict__ in,
                                             u16* __restrict__ out, int n4) {
    for (int i = blockIdx.x * 256 + threadIdx.x; i < n4; i += gridDim.x * 256) {
        float4 v = ((const float4*)in)[i];
        ushort4 u;
        u.x = f2bf(v.x); u.y = f2bf(v.y); u.z = f2bf(v.z); u.w = f2bf(v.w);
        ((ushort4*)out)[i] = u;
    }
}

// ---------- embed: h = x + wpe[study_date] ----------
__global__ __launch_bounds__(256) void embed_k(const float* __restrict__ x,
                                               const int* __restrict__ sd,
                                               const float* __restrict__ wpe,
                                               float* __restrict__ h) {
    int idx = blockIdx.x * 256 + threadIdx.x;          // over 8192*192 float4s
    int e4 = idx % 192;
    int bs = idx / 192;
    int b = bs >> 10;
    int t = (bs >> 5) & 31;
    int date = sd[b * 32 + t];
    date = date < 0 ? 0 : (date > 49 ? 49 : date);
    float4 xv = ((const float4*)x)[idx];
    float4 pv = ((const float4*)wpe)[date * 192 + e4];
    float4 r; r.x = xv.x + pv.x; r.y = xv.y + pv.y; r.z = xv.z + pv.z; r.w = xv.w + pv.w;
    ((float4*)h)[idx] = r;
}

// ---------- layernorm: wave per token ----------
template <bool BF16OUT>
__global__ __launch_bounds__(256) void ln_k(const float* __restrict__ in,
                                            const float* __restrict__ w,
                                            const float* __restrict__ b,
                                            void* __restrict__ out) {
    int tid = threadIdx.x, wv = tid >> 6, lane = tid & 63;
    int token = blockIdx.x * 4 + wv;
    const float4* ip = (const float4*)(in + (size_t)token * EE);
    float4 v[3];
#pragma unroll
    for (int p = 0; p < 3; p++) v[p] = ip[p * 64 + lane];
    float s = 0.f;
#pragma unroll
    for (int p = 0; p < 3; p++) s += v[p].x + v[p].y + v[p].z + v[p].w;
#pragma unroll
    for (int m = 1; m < 64; m <<= 1) s += __shfl_xor(s, m);
    float mean = s * (1.f / 768.f);
    float vs = 0.f;
#pragma unroll
    for (int p = 0; p < 3; p++) {
        float dx = v[p].x - mean, dy = v[p].y - mean, dz = v[p].z - mean, dw = v[p].w - mean;
        vs += dx * dx + dy * dy + dz * dz + dw * dw;
    }
#pragma unroll
    for (int m = 1; m < 64; m <<= 1) vs += __shfl_xor(vs, m);
    float rstd = rsqrtf(vs * (1.f / 768.f) + 1e-5f);
    const float4* wp = (const float4*)w;
    const float4* bp = (const float4*)b;
#pragma unroll
    for (int p = 0; p < 3; p++) {
        float4 wv4 = wp[p * 64 + lane], bv4 = bp[p * 64 + lane];
        float rx = (v[p].x - mean) * rstd * wv4.x + bv4.x;
        float ry = (v[p].y - mean) * rstd * wv4.y + bv4.y;
        float rz = (v[p].z - mean) * rstd * wv4.z + bv4.z;
        float rw = (v[p].w - mean) * rstd * wv4.w + bv4.w;
        if (BF16OUT) {
            ushort4 u; u.x = f2bf(rx); u.y = f2bf(ry); u.z = f2bf(rz); u.w = f2bf(rw);
            ((ushort4*)((u16*)out + (size_t)token * EE))[p * 64 + lane] = u;
        } else {
            float4 r; r.x = rx; r.y = ry; r.z = rz; r.w = rw;
            ((float4*)((float*)out + (size_t)token * EE))[p * 64 + lane] = r;
        }
    }
}

// ---------- GEMM: C[M,N] = A[M,K](bf16) * Bw[N,K]^T(bf16) + bias ----------
// 1-D grid, XCD-aware remap: id%8 = XCD owns a contiguous band of M-tiles,
// walking N fastest (A band L2-resident, B streamed).
// Unified vmcnt-gated software pipeline (never vmcnt(0) in steady state, so
// prefetch stays in flight across the barrier — the __syncthreads vmcnt(0)
// drain was the ~3700 cyc/iter stall):
//   BM=128: 3-stage LDS, prefetch distance 1, s_waitcnt vmcnt(4)+s_barrier
//   BM=64:  4-stage LDS, prefetch distance 2, s_waitcnt vmcnt(6)+s_barrier
// Stage safety: writer stage (ki+PD)%NST vs slowest reader (ki-1)%NST differ
// by PD+1 mod NST (2 mod 3 / 3 mod 4) -> always distinct. 48 KB LDS both ways
// -> 3 blocks/CU.
// MODE 0: QKV epilogue  (q -> qT [B,H,S,HD]; k -> kT [B,H,S,HD]; v -> vT [B,H,HD,S])
// MODE 1: residual      (hres[M,N] += C + bias)
// MODE 2: NewGELU       (outb[M,N] = bf16(gelu(C + bias)))
template <int MODE, int BM>
__global__ __launch_bounds__(256) void gemm_bt(const u16* __restrict__ A,
                                               const u16* __restrict__ Bw,
                                               const float* __restrict__ bias,
                                               float* __restrict__ hres,
                                               u16* __restrict__ outb,
                                               u16* __restrict__ vT,
                                               u16* __restrict__ kT,
                                               int M, int N, int K) {
    constexpr int TM = BM / 32;              // acc m-tiles per wave (4 or 2)
    constexpr int NST = (BM == 128) ? 3 : 4; // pipeline stages
    constexpr int PD = NST - 2;              // prefetch distance (1 or 2)
    constexpr int ATILE = BM * 32;           // u16 per A stage
    constexpr int TILE = ATILE + 4096;       // u16 per stage (A+B)
    constexpr int SSTR = TILE * 2;           // stage stride bytes
    __shared__ u16 SM[NST * TILE];

    const int tid = threadIdx.x;
    const int lane = tid & 63, w = tid >> 6;
    const int quad = lane >> 4, l16 = lane & 15;

    // XCD-aware block remap
    const int nx = N >> 7;
    const int ny = M / BM;
    const int id = blockIdx.x;
    const int xcd = id & 7, s = id >> 3;
    const int yt = xcd * (ny >> 3) + s / nx;
    const int xt = s % nx;
    const int m0 = yt * BM, n0 = xt * 128;
    const int wm = (w >> 1) * (BM / 2), wn = (w & 1) * 64;

    f32x4 acc[TM][4];
#pragma unroll
    for (int i = 0; i < TM; i++)
#pragma unroll
        for (int j = 0; j < 4; j++) acc[i][j] = (f32x4){0.f, 0.f, 0.f, 0.f};

    const int swz = (quad ^ ((l16 >> 1) & 3)) * 8;
    const int nk = K >> 5;

    // staging: chunk c holds row (c>>2), k-chunk ((c&3)^((c>>3)&3))
    // B: 512 chunks, 2 per thread
    const int cB0 = w * 128 + lane, cB1 = cB0 + 64;
    const int rB0 = cB0 >> 2, gB0 = (((cB0 & 3) ^ ((cB0 >> 3) & 3)) * 8);
    const int rB1 = cB1 >> 2, gB1 = (((cB1 & 3) ^ ((cB1 >> 3) & 3)) * 8);
    const u16* Bp0 = Bw + (size_t)(n0 + rB0) * K + gB0;
    const u16* Bp1 = Bw + (size_t)(n0 + rB1) * K + gB1;
    char* lB0 = (char*)SM + ATILE * 2 + w * 2048;
    char* lB1 = lB0 + 1024;
    // A: BM*4 chunks (2 per thread at BM=128, 1 at BM=64)
    const int cA0 = (BM == 128) ? cB0 : tid;
    const int rA0 = cA0 >> 2, gA0 = (((cA0 & 3) ^ ((cA0 >> 3) & 3)) * 8);
    const u16* Ap0 = A + (size_t)(m0 + rA0) * K + gA0;
    char* lA0 = (char*)SM + ((BM == 128) ? w * 2048 : w * 1024);
    const int cA1 = cB1;
    const int rA1 = cA1 >> 2, gA1 = (((cA1 & 3) ^ ((cA1 >> 3) & 3)) * 8);
    const u16* Ap1 = A + (size_t)(m0 + rA1) * K + gA1;
    char* lA1 = (char*)SM + w * 2048 + 1024;

    // prologue: stage tiles 0..PD-1
    g2l16(Ap0, lA0);
    if (BM == 128) g2l16(Ap1, lA1);
    g2l16(Bp0, lB0);
    g2l16(Bp1, lB1);
    if (PD == 2) {
        g2l16(Ap0 + 32, lA0 + SSTR);
        if (BM == 128) g2l16(Ap1 + 32, lA1 + SSTR);
        g2l16(Bp0 + 32, lB0 + SSTR);
        g2l16(Bp1 + 32, lB1 + SSTR);
    }

    int rb = 0, wb = PD;
    for (int ki = 0; ki < nk; ki++) {
        if (ki + PD < nk) {
            const int kb = (ki + PD) << 5;
            const int bo = wb * SSTR;
            g2l16(Ap0 + kb, lA0 + bo);
            if (BM == 128) g2l16(Ap1 + kb, lA1 + bo);
            g2l16(Bp0 + kb, lB0 + bo);
            g2l16(Bp1 + kb, lB1 + bo);
        }
        // gate: tile ki landed when <= PD tiles' loads remain outstanding
        if (BM == 128) {
            if (ki < nk - 1) __builtin_amdgcn_s_waitcnt(0x0F74);  // vmcnt(4)
            else             __builtin_amdgcn_s_waitcnt(0x0F70);  // vmcnt(0)
        } else {
            if (ki < nk - 2)      __builtin_amdgcn_s_waitcnt(0x0F76);  // vmcnt(6)
            else if (ki == nk - 2) __builtin_amdgcn_s_waitcnt(0x0F73); // vmcnt(3)
            else                  __builtin_amdgcn_s_waitcnt(0x0F70);  // vmcnt(0)
        }
        __builtin_amdgcn_s_barrier();

        const u16* Ab = (const u16*)SM + rb * TILE;
        const u16* Bb = Ab + ATILE;
        bf16x8 af[TM], bfr[4];
#pragma unroll
        for (int t = 0; t < TM; t++)
            af[t] = *(const bf16x8*)(Ab + (wm + t * 16 + l16) * 32 + swz);
#pragma unroll
        for (int t = 0; t < 4; t++)
            bfr[t] = *(const bf16x8*)(Bb + (wn + t * 16 + l16) * 32 + swz);
#pragma unroll
        for (int tm = 0; tm < TM; tm++)
#pragma unroll
            for (int tn = 0; tn < 4; tn++)
                acc[tm][tn] = __builtin_amdgcn_mfma_f32_16x16x32_bf16(
                    af[tm], bfr[tn], acc[tm][tn], 0, 0, 0);
        rb = (rb + 1 == NST) ? 0 : rb + 1;
        wb = (wb + 1 == NST) ? 0 : wb + 1;
    }

    // epilogue: C row = m0+wm+tm*16+quad*4+r ; col = n0+wn+tn*16+l16
#pragma unroll
    for (int tm = 0; tm < TM; tm++) {
        int rowm = m0 + wm + tm * 16 + quad * 4;
#pragma unroll
        for (int tn = 0; tn < 4; tn++) {
            int coln = n0 + wn + tn * 16 + l16;
            float bv = bias[coln];
            f32x4 v = acc[tm][tn];
            if (MODE == 0) {
                int b = rowm >> 10, s2 = rowm & 1023;
                if (coln < EE) {
                    int hh = coln >> 6, d = coln & 63;
                    u16* qp = outb + ((size_t)(b * HH + hh) * SS + s2) * HD + d;
#pragma unroll
                    for (int r = 0; r < 4; r++) qp[r * HD] = f2bf(v[r] + bv);
                } else if (coln < 2 * EE) {
                    int hh = (coln - EE) >> 6, d = (coln - EE) & 63;
                    u16* kp = kT + ((size_t)(b * HH + hh) * SS + s2) * HD + d;
#pragma unroll
                    for (int r = 0; r < 4; r++) kp[r * HD] = f2bf(v[r] + bv);
                } else {
                    int hh = (coln - 2 * EE) >> 6, d = (coln - 2 * EE) & 63;
                    ushort4 pk;
                    pk.x = f2bf(v[0] + bv); pk.y = f2bf(v[1] + bv);
                    pk.z = f2bf(v[2] + bv); pk.w = f2bf(v[3] + bv);
                    *(ushort4*)(vT + (((size_t)((b * HH + hh) * HD + d)) << 10) + s2) = pk;
                }
            } else if (MODE == 1) {
#pragma unroll
                for (int r = 0; r < 4; r++) {
                    size_t idx = (size_t)(rowm + r) * N + coln;
                    hres[idx] += v[r] + bv;
                }
            } else {
#pragma unroll
                for (int r = 0; r < 4; r++) {
                    float x = v[r] + bv;
                    float t = x + 0.044715f * x * x * x;
                    float e = __expf(-1.5957691216057308f * t);  // exp(-2*sqrt(2/pi)*t)
                    float th = (1.f - e) / (1.f + e);
                    outb[(size_t)(rowm + r) * N + coln] = f2bf(0.5f * x * (1.f + th));
                }
            }
        }
    }
}

// ---------- flash attention ----------
// qT,kT: [B,H,S,HD] bf16   vT: [B,H,HD,S] bf16   o: [B*S, 768] bf16
// block = 4 waves = one (b, head, 64 q-rows); K/V tiles staged in LDS, shared by all waves.
// Block-causal: waves 0,1 (rows q0..q0+31) see keys < q0+32; waves 2,3 see < q0+64.
__global__ __launch_bounds__(256) void attn_k(const u16* __restrict__ qT,
                                              const u16* __restrict__ kT,
                                              const u16* __restrict__ vT,
                                              u16* __restrict__ o) {
    __shared__ u16 Ks[2048];        // 32 tokens x 64 d, 16B chunks swizzled
    __shared__ u16 Vs[2048];        // 64 d x 32 tokens, 16B chunks swizzled
    __shared__ u16 P[4][16 * 40];   // per-wave P tile
    int tid = threadIdx.x, w = tid >> 6, lane = tid & 63;
    int quad = lane >> 4, l16 = lane & 15;
    int blk = blockIdx.x;
    int qg = 15 - (blk / 96);       // largest q-groups dispatch first (load balance)
    int bh = blk % 96;              // b*12 + h
    int b = bh / HH, hh = bh % HH;
    int q0 = qg * 64;
    int kend_blk = q0 + 64;
    int kend_w = q0 + ((w >> 1) ? 64 : 32);

    const u16* qbase = qT + ((size_t)bh * SS + q0 + w * 16 + l16) * HD + quad * 8;
    bf16x8 qf0 = *(const bf16x8*)(qbase);
    bf16x8 qf1 = *(const bf16x8*)(qbase + 32);

    f32x4 of[4];
#pragma unroll
    for (int i = 0; i < 4; i++) of[i] = (f32x4){0.f, 0.f, 0.f, 0.f};
    float mrun[4], lrun[4];
#pragma unroll
    for (int r = 0; r < 4; r++) { mrun[r] = -__builtin_inff(); lrun[r] = 0.f; }

    // staging addresses: slot s (=tid) of Ks holds K[token=s>>3][dchunk=(s&7)^(token&7)]
    int tK = tid >> 3, dcK = ((tid & 7) ^ (tK & 7));
    const u16* kg = kT + ((size_t)bh * SS + tK) * HD + dcK * 8;
    char* kl = (char*)Ks + w * 1024;
    // slot s of Vs holds V[d=s>>2][tokchunk=(s&3)^((d>>1)&3)]
    int dV = tid >> 2, tcV = ((tid & 3) ^ ((dV >> 1) & 3));
    const u16* vg = vT + ((size_t)bh * HD + dV) * SS + tcV * 8;
    char* vl = (char*)Vs + w * 1024;
    u16* Pw = P[w];

    for (int kb = 0; kb < kend_blk; kb += 32) {
        g2l16(kg + (size_t)kb * HD, kl);
        g2l16(vg + kb, vl);
        __syncthreads();
        if (kb < kend_w) {
            int t0 = l16, t1 = 16 + l16;
            bf16x8 k00 = *(const bf16x8*)(Ks + (t0 * 8 + (quad ^ (l16 & 7))) * 8);
            bf16x8 k01 = *(const bf16x8*)(Ks + (t0 * 8 + ((4 + quad) ^ (l16 & 7))) * 8);
            bf16x8 k10 = *(const bf16x8*)(Ks + (t1 * 8 + (quad ^ (l16 & 7))) * 8);
            bf16x8 k11 = *(const bf16x8*)(Ks + (t1 * 8 + ((4 + quad) ^ (l16 & 7))) * 8);
            f32x4 s0 = (f32x4){0.f, 0.f, 0.f, 0.f};
            f32x4 s1 = (f32x4){0.f, 0.f, 0.f, 0.f};
            s0 = __builtin_amdgcn_mfma_f32_16x16x32_bf16(qf0, k00, s0, 0, 0, 0);
            s0 = __builtin_amdgcn_mfma_f32_16x16x32_bf16(qf1, k01, s0, 0, 0, 0);
            s1 = __builtin_amdgcn_mfma_f32_16x16x32_bf16(qf0, k10, s1, 0, 0, 0);
            s1 = __builtin_amdgcn_mfma_f32_16x16x32_bf16(qf1, k11, s1, 0, 0, 0);

            float alpha[4];
#pragma unroll
            for (int r = 0; r < 4; r++) {
                float a0 = s0[r] * 0.125f, a1 = s1[r] * 0.125f;
                float mx = fmaxf(a0, a1);
#pragma unroll
                for (int m = 1; m < 16; m <<= 1) mx = fmaxf(mx, __shfl_xor(mx, m));
                float mnew = fmaxf(mrun[r], mx);
                alpha[r] = __expf(mrun[r] - mnew);
                float p0 = __expf(a0 - mnew);
                float p1 = __expf(a1 - mnew);
                float ps = p0 + p1;
#pragma unroll
                for (int m = 1; m < 16; m <<= 1) ps += __shfl_xor(ps, m);
                lrun[r] = lrun[r] * alpha[r] + ps;
                mrun[r] = mnew;
                Pw[(quad * 4 + r) * 40 + l16] = f2bf(p0);
                Pw[(quad * 4 + r) * 40 + 16 + l16] = f2bf(p1);
            }
#pragma unroll
            for (int n4 = 0; n4 < 4; n4++) {
                of[n4][0] *= alpha[0]; of[n4][1] *= alpha[1];
                of[n4][2] *= alpha[2]; of[n4][3] *= alpha[3];
            }
            // P round-trip is per-wave: only lgkmcnt ordering needed, no barrier
            bf16x8 pf = *(const bf16x8*)(Pw + l16 * 40 + quad * 8);
#pragma unroll
            for (int n4 = 0; n4 < 4; n4++) {
                int d = n4 * 16 + l16;
                bf16x8 vf = *(const bf16x8*)(Vs + (d * 4 + (quad ^ ((d >> 1) & 3))) * 8);
                of[n4] = __builtin_amdgcn_mfma_f32_16x16x32_bf16(pf, vf, of[n4], 0, 0, 0);
            }
        }
        __syncthreads();
    }

    float inv[4];
#pragma unroll
    for (int r = 0; r < 4; r++) inv[r] = 1.f / lrun[r];
#pragma unroll
    for (int n4 = 0; n4 < 4; n4++)
#pragma unroll
        for (int r = 0; r < 4; r++)
            o[(size_t)(b * SS + q0 + w * 16 + quad * 4 + r) * EE + hh * HD + n4 * 16 + l16] =
                f2bf(of[n4][r] * inv[r]);
}

// ---------- launcher ----------
extern "C" void kernel_launch(void* const* d_in, const int* in_sizes, int n_in,
                              void* d_out, int out_size, void* d_ws, size_t ws_size,
                              hipStream_t stream) {
    const float* x     = (const float*)d_in[0];
    const int*   sd    = (const int*)d_in[1];
    const float* wpe   = (const float*)d_in[2];
    const float* ln1w  = (const float*)d_in[3];
    const float* ln1b  = (const float*)d_in[4];
    const float* in_w  = (const float*)d_in[5];
    const float* in_b  = (const float*)d_in[6];
    const float* out_w = (const float*)d_in[7];
    const float* out_b = (const float*)d_in[8];
    const float* ln2w  = (const float*)d_in[9];
    const float* ln2b  = (const float*)d_in[10];
    const float* fc_w  = (const float*)d_in[11];
    const float* fc_b  = (const float*)d_in[12];
    const float* pr_w  = (const float*)d_in[13];
    const float* pr_b  = (const float*)d_in[14];
    const float* lnfw  = (const float*)d_in[15];
    const float* lnfb  = (const float*)d_in[16];
    float* outp = (float*)d_out;

    char* ws = (char*)d_ws;
    float* h   = (float*)ws;                        // 25,165,824 B
    u16* ybuf  = (u16*)(ws + 25165824);             // 12,582,912 B
    u16* big   = (u16*)(ws + 37748736);             // 50,331,648 B (qT+kT / fc act)
    u16* qT    = big;                               // 6,291,456 elems
    u16* kT    = big + 6291456;                     // 6,291,456 elems
    u16* vT    = (u16*)(ws + 88080384);             // 12,582,912 B
    u16* wb    = (u16*)(ws + 100663296);            // 56,623,104 B
    u16* w_in  = wb;                                // 4*2304*768
    u16* w_out = w_in + 7077888;                    // 4*768*768
    u16* w_fc  = w_out + 2359296;                   // 4*3072*768
    u16* w_pr  = w_fc + 9437184;                    // 4*768*3072

    cvt_k<<<1024, 256, 0, stream>>>(in_w,  w_in,  7077888 / 4);
    cvt_k<<<1024, 256, 0, stream>>>(out_w, w_out, 2359296 / 4);
    cvt_k<<<1024, 256, 0, stream>>>(fc_w,  w_fc,  9437184 / 4);
    cvt_k<<<1024, 256, 0, stream>>>(pr_w,  w_pr,  9437184 / 4);
    embed_k<<<6144, 256, 0, stream>>>(x, sd, wpe, h);

    for (int l = 0; l < LL; l++) {
        ln_k<true><<<2048, 256, 0, stream>>>(h, ln1w + l * EE, ln1b + l * EE, ybuf);
        gemm_bt<0, 128><<<18 * 64, 256, 0, stream>>>(
            ybuf, w_in + (size_t)l * 2304 * 768, in_b + l * 2304, nullptr, qT, vT, kT,
            8192, 2304, 768);
        attn_k<<<1536, 256, 0, stream>>>(qT, kT, vT, ybuf);
        gemm_bt<1, 64><<<6 * 128, 256, 0, stream>>>(
            ybuf, w_out + (size_t)l * 768 * 768, out_b + l * 768, h, nullptr, nullptr, nullptr,
            8192, 768, 768);
        ln_k<true><<<2048, 256, 0, stream>>>(h, ln2w + l * EE, ln2b + l * EE, ybuf);
        gemm_bt<2, 128><<<24 * 64, 256, 0, stream>>>(
            ybuf, w_fc + (size_t)l * 3072 * 768, fc_b + l * 3072, nullptr, big, nullptr, nullptr,
            8192, 3072, 768);
        gemm_bt<1, 64><<<6 * 128, 256, 0, stream>>>(
            big, w_pr + (size_t)l * 768 * 3072, pr_b + l * 768, h, nullptr, nullptr, nullptr,
            8192, 768, 3072);
    }
    ln_k<false><<<2048, 256, 0, stream>>>(h, lnfw, lnfb, outp);
}